// Round 5
// baseline (192.197 us; speedup 1.0000x reference)
//
#include <hip/hip_runtime.h>
#include <hip/hip_bf16.h>
#include <math.h>

// ---------------------------------------------------------------------------
// CrossCausalAttentionBlock on MI355X (gfx950)
// B=8, T=1024 (V=4 blocks of 256), C=512, NH=8, hd=64
// R5: prep gather phase-1 vectorized to float4 (was 32 scalar 4B loads/thread,
//     latency-bound at 2.3 TB/s). Rest unchanged from R4.
// ---------------------------------------------------------------------------

typedef __bf16 bf16;
typedef __bf16 bf16x8 __attribute__((ext_vector_type(8)));
typedef __bf16 bf16x4 __attribute__((ext_vector_type(4)));
typedef float  f32x4  __attribute__((ext_vector_type(4)));

__device__ __forceinline__ void gload_lds16(const void* g, void* l) {
  __builtin_amdgcn_global_load_lds(
      (__attribute__((address_space(1))) void*)(g),
      (__attribute__((address_space(3))) void*)(l), 16, 0, 0);
}

// ---------------------------------------------------------------------------
// Kernel 1: prep = all weight converts (blocks 0..3071) + gather+LN1 (3072..4607)
// ---------------------------------------------------------------------------
__global__ __launch_bounds__(256)
void prep_k(const float* __restrict__ Wq, const float* __restrict__ Wkv,
            const float* __restrict__ Wo, const float* __restrict__ Wfc,
            const float* __restrict__ Wpr,
            bf16* __restrict__ WqT, bf16* __restrict__ WkvT,
            bf16* __restrict__ WoT, bf16* __restrict__ WfcT,
            bf16* __restrict__ WprT,
            const float* __restrict__ xi, const float* __restrict__ xj,
            const float* __restrict__ xc,
            const float* __restrict__ g, const float* __restrict__ bb,
            bf16* __restrict__ qs, bf16* __restrict__ kvs,
            float* __restrict__ cs0)
{
  __shared__ __align__(16) float smemf[512 * 17]; // 34816 B
  const int t = blockIdx.x;
  const int tid = threadIdx.x;
  if (t < 3072) { // ---- weight transpose-convert, 32x32 tiles
    const float* W; bf16* Wt; int K, N, lognx, tl;
    if (t < 256)       { W = Wq;  Wt = WqT;  K = 512;  N = 512;  lognx = 4; tl = t; }
    else if (t < 768)  { W = Wkv; Wt = WkvT; K = 512;  N = 1024; lognx = 5; tl = t - 256; }
    else if (t < 1024) { W = Wo;  Wt = WoT;  K = 512;  N = 512;  lognx = 4; tl = t - 768; }
    else if (t < 2048) { W = Wfc; Wt = WfcT; K = 512;  N = 2048; lognx = 6; tl = t - 1024; }
    else               { W = Wpr; Wt = WprT; K = 2048; N = 512;  lognx = 4; tl = t - 2048; }
    const int bx = tl & ((1 << lognx) - 1), by = tl >> lognx;
    float (*tt)[33] = (float (*)[33])smemf;
    const int x = tid & 31, y = tid >> 5;
    const int n0 = bx << 5, k0 = by << 5;
#pragma unroll
    for (int yy = y; yy < 32; yy += 8)
      tt[yy][x] = W[(size_t)(k0 + yy) * N + n0 + x];
    __syncthreads();
#pragma unroll
    for (int yy = y; yy < 32; yy += 8)
      Wt[(size_t)(n0 + yy) * K + k0 + x] = (bf16)tt[x][yy];
    return;
  }
  // ---- gather [v,b,c,h,w] -> [b,t,c] + LN1
  const int u = t - 3072;
  const int sel = u >> 9, bid = u & 511;
  const int hh = bid & 15, b = (bid >> 4) & 7, v = bid >> 7;
  const float* src = (sel == 0) ? xi : ((sel == 1) ? xj : xc);
  const size_t base = ((size_t)(v * 8 + b) * 512) * 256 + (size_t)hh * 16;
  float* tile = smemf;
  { // phase 1: float4 vectorized gather. thread = (chb = tid>>2, w4 = tid&3)
    const int w4 = (tid & 3) << 2, chb = tid >> 2;
#pragma unroll
    for (int k = 0; k < 8; ++k) {
      const int ch = chb + (k << 6);
      const f32x4 vv = *(const f32x4*)&src[base + (size_t)ch * 256 + w4];
#pragma unroll
      for (int i = 0; i < 4; ++i)
        tile[ch * 17 + w4 + i] = vv[i];
    }
  }
  __syncthreads();
  const int w2 = tid >> 4, cg2 = tid & 15;
  float s = 0.f, ss = 0.f;
#pragma unroll
  for (int k = 0; k < 32; ++k) {
    float x = tile[(cg2 + (k << 4)) * 17 + w2];
    s += x; ss += x * x;
  }
#pragma unroll
  for (int off = 1; off < 16; off <<= 1) {
    s += __shfl_xor(s, off);
    ss += __shfl_xor(ss, off);
  }
  const float mu = s * (1.f / 512.f);
  const float rstd = rsqrtf(ss * (1.f / 512.f) - mu * mu + 1e-5f);
  const int tk = v * 256 + hh * 16 + w2;
  const size_t orow = ((size_t)b * 1024 + tk) * 512;
#pragma unroll
  for (int k = 0; k < 32; ++k) {
    int ch = cg2 + (k << 4);
    float x = (tile[ch * 17 + w2] - mu) * rstd * g[ch] + bb[ch];
    if (sel == 0)      qs[orow + ch]  = (bf16)x;
    else if (sel == 1) kvs[orow + ch] = (bf16)x;
    else               cs0[orow + ch] = x;
  }
}

// ---------------------------------------------------------------------------
// Kernel 3: row LayerNorm(ln2) on cs f32[8192][512] -> hcs bf16. 1 wave/row.
// ---------------------------------------------------------------------------
__global__ __launch_bounds__(256)
void ln2_k(const float* __restrict__ cs, const float* __restrict__ g,
           const float* __restrict__ bb, bf16* __restrict__ hcs)
{
  const int tid = threadIdx.x, wid = tid >> 6, lane = tid & 63;
  const int row = blockIdx.x * 4 + wid;
  const float* x = cs + (size_t)row * 512 + lane * 8;
  float v[8];
  *(f32x4*)&v[0] = *(const f32x4*)&x[0];
  *(f32x4*)&v[4] = *(const f32x4*)&x[4];
  float s = 0.f, ss = 0.f;
#pragma unroll
  for (int k = 0; k < 8; ++k) { s += v[k]; ss += v[k] * v[k]; }
#pragma unroll
  for (int off = 1; off < 64; off <<= 1) {
    s += __shfl_xor(s, off);
    ss += __shfl_xor(ss, off);
  }
  const float mu = s * (1.f / 512.f);
  const float rstd = rsqrtf(ss * (1.f / 512.f) - mu * mu + 1e-5f);
  bf16x8 o;
#pragma unroll
  for (int k = 0; k < 8; ++k) {
    int ch = lane * 8 + k;
    o[k] = (bf16)((v[k] - mu) * rstd * g[ch] + bb[ch]);
  }
  *(bf16x8*)&hcs[(size_t)row * 512 + lane * 8] = o;
}

// ---------------------------------------------------------------------------
// Kernel 4: FC GEMM (M=8192, N=2048, K=512), 2-phase dbuf, GELU epilogue
// staged through padded LDS (stride 132) for full-line coalesced stores.
// ---------------------------------------------------------------------------
__global__ __launch_bounds__(256)
void gemm_fc_k(const bf16* __restrict__ A, const bf16* __restrict__ Bt,
               const float* __restrict__ bias, bf16* __restrict__ fo)
{
  const int K = 512;
  __shared__ __align__(16) char smem[34816];
  bf16* As = (bf16*)smem;            // [2][4096]
  bf16* Bs = (bf16*)(smem + 16384);  // [2][4096]
  const int tid = threadIdx.x;
  const int wid = tid >> 6, lane = tid & 63;
  const int wr = wid >> 1, wc = wid & 1;
  const int ml = lane & 15, kg = (lane >> 4) << 3;
  const int m0 = blockIdx.x * 128, n0 = blockIdx.y * 128;

  const int e0 = wid * 512 + lane * 8;
  const int r0 = e0 >> 5, c0 = e0 & 31;
  const int e1 = e0 + 2048;
  const int r1 = e1 >> 5, c1 = e1 & 31;

  const bf16* Ag = A + (size_t)m0 * K;
  const bf16* Bg = Bt + (size_t)n0 * K;

  f32x4 acc[4][4] = {};

  gload_lds16(Ag + (size_t)r0 * K + c0, As + wid * 512);
  gload_lds16(Ag + (size_t)r1 * K + c1, As + 2048 + wid * 512);
  gload_lds16(Bg + (size_t)r0 * K + c0, Bs + wid * 512);
  gload_lds16(Bg + (size_t)r1 * K + c1, Bs + 2048 + wid * 512);

  int cur = 0;
  for (int k0 = 0; k0 < K; k0 += 32) {
    __syncthreads();
    if (k0 + 32 < K) {
      const int nb = cur ^ 1, kn = k0 + 32;
      gload_lds16(Ag + (size_t)r0 * K + kn + c0, As + nb * 4096 + wid * 512);
      gload_lds16(Ag + (size_t)r1 * K + kn + c1, As + nb * 4096 + 2048 + wid * 512);
      gload_lds16(Bg + (size_t)r0 * K + kn + c0, Bs + nb * 4096 + wid * 512);
      gload_lds16(Bg + (size_t)r1 * K + kn + c1, Bs + nb * 4096 + 2048 + wid * 512);
    }
    bf16x8 af[4], bfr[4];
#pragma unroll
    for (int mf = 0; mf < 4; ++mf)
      af[mf] = *(const bf16x8*)&As[cur * 4096 + (wr * 64 + mf * 16 + ml) * 32 + kg];
#pragma unroll
    for (int nf = 0; nf < 4; ++nf)
      bfr[nf] = *(const bf16x8*)&Bs[cur * 4096 + (wc * 64 + nf * 16 + ml) * 32 + kg];
#pragma unroll
    for (int mf = 0; mf < 4; ++mf)
#pragma unroll
      for (int nf = 0; nf < 4; ++nf)
        acc[mf][nf] = __builtin_amdgcn_mfma_f32_16x16x32_bf16(
            af[mf], bfr[nf], acc[mf][nf], 0, 0, 0);
    cur ^= 1;
  }

  // GELU -> padded LDS tile (stride 132) -> coalesced 16B row stores
  __syncthreads();
  bf16* OT = (bf16*)smem; // [128][132]
  const int jrow0 = (lane >> 4) << 2;
#pragma unroll
  for (int nf = 0; nf < 4; ++nf) {
    const float bv = bias[n0 + wc * 64 + nf * 16 + ml];
#pragma unroll
    for (int mf = 0; mf < 4; ++mf)
#pragma unroll
      for (int j = 0; j < 4; ++j) {
        float x = acc[mf][nf][j] + bv;
        float u = 0.7978845608f * (x + 0.044715f * x * x * x);
        float e = __expf(2.f * u);
        float th = 1.f - 2.f / (e + 1.f);
        OT[(wr * 64 + mf * 16 + jrow0 + j) * 132 + wc * 64 + nf * 16 + ml] =
            (bf16)(0.5f * x * (1.f + th));
      }
  }
  __syncthreads();
#pragma unroll
  for (int it = 0; it < 8; ++it) {
    const int idx = it * 256 + tid;
    const int cg = idx & 15, r = idx >> 4;
    *(bf16x8*)&fo[(size_t)(m0 + r) * 2048 + n0 + cg * 8] =
        *(const bf16x8*)&OT[r * 132 + cg * 8];
  }
}

// ---------------------------------------------------------------------------
// Kernel 4b: in-block split-K GEMM for N=512 stages (O, PR). 512 threads,
// 2 wave-groups x K-half, 2-phase dbuf each; LDS combine; group 1 epilogues.
// ---------------------------------------------------------------------------
enum { EPI_O = 2, EPI_PR = 4 };

template <int EPI>
__global__ __launch_bounds__(512)
void gemmsk_k(const bf16* __restrict__ A, const bf16* __restrict__ Bt,
              const float* __restrict__ bias, const float* res,
              void* out0, int K)
{
  __shared__ __align__(16) char smem[131072];
  bf16*  AS = (bf16*)smem;
  bf16*  BS = (bf16*)(smem + 65536);
  float* CF = (float*)smem;

  const int tid = threadIdx.x;
  const int wid = tid >> 6, lane = tid & 63;
  const int half = wid >> 2, w2 = wid & 3;
  const int wr = w2 >> 1, wc = w2 & 1;
  const int ml = lane & 15, kg = (lane >> 4) << 3;
  const int m0 = blockIdx.x * 128, n0 = blockIdx.y * 128;
  const int Kh = K >> 1;

  const int e0 = w2 * 512 + lane * 8;
  const int r0 = e0 >> 5, c0 = e0 & 31;
  const int e1 = e0 + 2048;
  const int r1 = e1 >> 5, c1 = e1 & 31;

  const bf16* Ag = A + (size_t)m0 * K + half * Kh;
  const bf16* Bg = Bt + (size_t)n0 * K + half * Kh;
  bf16* A0 = AS + half * 4096;
  bf16* B0 = BS + half * 4096;

  f32x4 acc[4][4] = {};

  gload_lds16(Ag + (size_t)r0 * K + c0, A0 + w2 * 512);
  gload_lds16(Ag + (size_t)r1 * K + c1, A0 + 2048 + w2 * 512);
  gload_lds16(Bg + (size_t)r0 * K + c0, B0 + w2 * 512);
  gload_lds16(Bg + (size_t)r1 * K + c1, B0 + 2048 + w2 * 512);

  int cur = 0;
  for (int k0 = 0; k0 < Kh; k0 += 32) {
    __syncthreads();
    if (k0 + 32 < Kh) {
      const int kn = k0 + 32;
      bf16* An = AS + ((cur ^ 1) * 8192) + half * 4096;
      bf16* Bn = BS + ((cur ^ 1) * 8192) + half * 4096;
      gload_lds16(Ag + (size_t)r0 * K + kn + c0, An + w2 * 512);
      gload_lds16(Ag + (size_t)r1 * K + kn + c1, An + 2048 + w2 * 512);
      gload_lds16(Bg + (size_t)r0 * K + kn + c0, Bn + w2 * 512);
      gload_lds16(Bg + (size_t)r1 * K + kn + c1, Bn + 2048 + w2 * 512);
    }
    const bf16* Ac = AS + cur * 8192 + half * 4096;
    const bf16* Bc = BS + cur * 8192 + half * 4096;
    bf16x8 af[4], bfr[4];
#pragma unroll
    for (int mf = 0; mf < 4; ++mf)
      af[mf] = *(const bf16x8*)&Ac[(wr * 64 + mf * 16 + ml) * 32 + kg];
#pragma unroll
    for (int nf = 0; nf < 4; ++nf)
      bfr[nf] = *(const bf16x8*)&Bc[(wc * 64 + nf * 16 + ml) * 32 + kg];
#pragma unroll
    for (int mf = 0; mf < 4; ++mf)
#pragma unroll
      for (int nf = 0; nf < 4; ++nf)
        acc[mf][nf] = __builtin_amdgcn_mfma_f32_16x16x32_bf16(
            af[mf], bfr[nf], acc[mf][nf], 0, 0, 0);
    cur ^= 1;
  }

  const int jrow0 = (lane >> 4) << 2;
  __syncthreads();
  if (half == 0) {
#pragma unroll
    for (int mf = 0; mf < 4; ++mf)
#pragma unroll
      for (int nf = 0; nf < 4; ++nf)
#pragma unroll
        for (int j = 0; j < 4; ++j)
          CF[(wr * 64 + mf * 16 + jrow0 + j) * 128 + wc * 64 + nf * 16 + ml] =
              acc[mf][nf][j];
  }
  __syncthreads();
  if (half == 1) {
#pragma unroll
    for (int nf = 0; nf < 4; ++nf) {
      const int n = n0 + wc * 64 + nf * 16 + ml;
      const float bv = bias[n];
#pragma unroll
      for (int mf = 0; mf < 4; ++mf) {
        const int mbase = m0 + wr * 64 + mf * 16 + jrow0;
        float v4[4];
#pragma unroll
        for (int j = 0; j < 4; ++j)
          v4[j] = acc[mf][nf][j] +
                  CF[(wr * 64 + mf * 16 + jrow0 + j) * 128 + wc * 64 + nf * 16 + ml];
        if constexpr (EPI == EPI_O) {
          float* cs = (float*)out0;
#pragma unroll
          for (int j = 0; j < 4; ++j) {
            const size_t idx = (size_t)(mbase + j) * 512 + n;
            cs[idx] = v4[j] + bv + res[idx];
          }
        } else {
          float* out = (float*)out0;
          const int b = mbase >> 10, t = mbase & 1023;
          const int v = t >> 8, hhh = (t >> 4) & 15, w0 = t & 15;
          f32x4 o;
#pragma unroll
          for (int j = 0; j < 4; ++j)
            o[j] = v4[j] + bv + res[(size_t)(mbase + j) * 512 + n];
          *(f32x4*)&out[(((size_t)v * 8 + b) * 512 + n) * 256 + hhh * 16 + w0] = o;
        }
      }
    }
  }
}

// ---------------------------------------------------------------------------
// Kernel 4c: merged Q + KV projection GEMM, 2-phase dbuf, LDS-staged stores.
// Grid (64, 12): ybl 0-3 Q, 4-7 K, 8-11 V(transposed).
// ---------------------------------------------------------------------------
__global__ __launch_bounds__(256)
void gemm_qkv_k(const bf16* __restrict__ Aq, const bf16* __restrict__ Akv,
                const bf16* __restrict__ WqT, const bf16* __restrict__ WkvT,
                const float* __restrict__ bq, const float* __restrict__ bkv,
                bf16* __restrict__ q_buf, bf16* __restrict__ k_buf,
                bf16* __restrict__ v_t)
{
  const int K = 512;
  __shared__ __align__(16) char smem[34816];
  bf16* As = (bf16*)smem;
  bf16* Bs = (bf16*)(smem + 16384);
  const int tid = threadIdx.x;
  const int wid = tid >> 6, lane = tid & 63;
  const int wr = wid >> 1, wc = wid & 1;
  const int ml = lane & 15, kg = (lane >> 4) << 3;
  const int ybl = blockIdx.y;
  const bool isq = ybl < 4;
  const bf16* A     = isq ? Aq  : Akv;
  const bf16* Bt    = isq ? WqT : WkvT;
  const float* bias = isq ? bq : bkv;
  const int n0 = isq ? (ybl << 7) : ((ybl - 4) << 7);
  const int m0 = blockIdx.x * 128;

  const int e0 = wid * 512 + lane * 8;
  const int r0 = e0 >> 5, c0 = e0 & 31;
  const int e1 = e0 + 2048;
  const int r1 = e1 >> 5, c1 = e1 & 31;

  const bf16* Ag = A + (size_t)m0 * K;
  const bf16* Bg = Bt + (size_t)n0 * K;

  f32x4 acc[4][4] = {};

  gload_lds16(Ag + (size_t)r0 * K + c0, As + wid * 512);
  gload_lds16(Ag + (size_t)r1 * K + c1, As + 2048 + wid * 512);
  gload_lds16(Bg + (size_t)r0 * K + c0, Bs + wid * 512);
  gload_lds16(Bg + (size_t)r1 * K + c1, Bs + 2048 + wid * 512);

  int cur = 0;
  for (int k0 = 0; k0 < K; k0 += 32) {
    __syncthreads();
    if (k0 + 32 < K) {
      const int nb = cur ^ 1, kn = k0 + 32;
      gload_lds16(Ag + (size_t)r0 * K + kn + c0, As + nb * 4096 + wid * 512);
      gload_lds16(Ag + (size_t)r1 * K + kn + c1, As + nb * 4096 + 2048 + wid * 512);
      gload_lds16(Bg + (size_t)r0 * K + kn + c0, Bs + nb * 4096 + wid * 512);
      gload_lds16(Bg + (size_t)r1 * K + kn + c1, Bs + nb * 4096 + 2048 + wid * 512);
    }
    bf16x8 af[4], bfr[4];
#pragma unroll
    for (int mf = 0; mf < 4; ++mf)
      af[mf] = *(const bf16x8*)&As[cur * 4096 + (wr * 64 + mf * 16 + ml) * 32 + kg];
#pragma unroll
    for (int nf = 0; nf < 4; ++nf)
      bfr[nf] = *(const bf16x8*)&Bs[cur * 4096 + (wc * 64 + nf * 16 + ml) * 32 + kg];
#pragma unroll
    for (int mf = 0; mf < 4; ++mf)
#pragma unroll
      for (int nf = 0; nf < 4; ++nf)
        acc[mf][nf] = __builtin_amdgcn_mfma_f32_16x16x32_bf16(
            af[mf], bfr[nf], acc[mf][nf], 0, 0, 0);
    cur ^= 1;
  }

  __syncthreads();
  bf16* OT = (bf16*)smem; // [128][132] padded
  const int jrow0 = (lane >> 4) << 2;
  const int b = m0 >> 10, t0 = m0 & 1023;
  if (ybl < 8) { // Q or K: stage row-major (row=m, col=n)
#pragma unroll
    for (int nf = 0; nf < 4; ++nf) {
      const float bv = bias[n0 + wc * 64 + nf * 16 + ml];
#pragma unroll
      for (int mf = 0; mf < 4; ++mf)
#pragma unroll
        for (int j = 0; j < 4; ++j)
          OT[(wr * 64 + mf * 16 + jrow0 + j) * 132 + wc * 64 + nf * 16 + ml] =
              (bf16)(acc[mf][nf][j] + bv);
    }
    __syncthreads();
    bf16* dst = isq ? q_buf : k_buf;
    const int h0 = n0 >> 6;
#pragma unroll
    for (int it = 0; it < 8; ++it) {
      const int idx = it * 256 + tid;
      const int dg = idx & 7, r = (idx >> 3) & 127, hl = idx >> 10;
      *(bf16x8*)&dst[(((size_t)b * 8 + h0 + hl) * 1024 + t0 + r) * 64 + dg * 8] =
          *(const bf16x8*)&OT[r * 132 + hl * 64 + dg * 8];
    }
  } else { // V: stage col-major (row=n col, col=m) for t-contiguous stores
#pragma unroll
    for (int nf = 0; nf < 4; ++nf) {
      const float bv = bias[n0 + wc * 64 + nf * 16 + ml];
#pragma unroll
      for (int mf = 0; mf < 4; ++mf) {
        bf16x4 o;
#pragma unroll
        for (int j = 0; j < 4; ++j) o[j] = (bf16)(acc[mf][nf][j] + bv);
        *(bf16x4*)&OT[(wc * 64 + nf * 16 + ml) * 132 + wr * 64 + mf * 16 + jrow0] = o;
      }
    }
    __syncthreads();
    const int h0 = (n0 - 512) >> 6;
#pragma unroll
    for (int it = 0; it < 8; ++it) {
      const int idx = it * 256 + tid;
      const int og = idx & 15, c = idx >> 4;
      const int hl = c >> 6, d = c & 63;
      *(bf16x8*)&v_t[(((size_t)b * 8 + h0 + hl) * 64 + d) * 1024 + t0 + og * 8] =
          *(const bf16x8*)&OT[c * 132 + og * 8];
    }
  }
}

// ---------------------------------------------------------------------------
// Kernel 5: block-causal flash attention (unchanged from R2/R3/R4).
// ---------------------------------------------------------------------------
__global__ __launch_bounds__(256)
void attn_k(const bf16* __restrict__ qb, const bf16* __restrict__ kb,
            const bf16* __restrict__ vt, bf16* __restrict__ y)
{
  __shared__ bf16 Ks[2][4096];
  __shared__ bf16 Vs[2][4096];
  __shared__ bf16 Ps[4][1024];
  const int tid = threadIdx.x, wid = tid >> 6, lane = tid & 63;
  const int L = blockIdx.x;
  const int xcd = L & 7, chunk = L >> 3;
  const int bh = xcd + ((chunk >> 4) << 3);
  const int qt = 15 - (chunk & 15);
  const int b = bh >> 3, h = bh & 7;
  const int t0 = qt << 6;
  const int ml = lane & 15, hi = lane >> 4, kg = hi << 3;

  const bf16* qrow = qb + ((size_t)bh * 1024 + t0 + wid * 16) * 64;
  bf16x8 aq[2];
  aq[0] = *(const bf16x8*)&qrow[ml * 64 + kg];
  aq[1] = *(const bf16x8*)&qrow[ml * 64 + 32 + kg];

  f32x4 accO[4] = {};
  float lsum[4] = {0.f, 0.f, 0.f, 0.f};

  const int nkt = ((qt >> 2) + 1) << 2;
  const bf16* kbase = kb + (size_t)bh * 1024 * 64;
  const bf16* vbase = vt + (size_t)bh * 64 * 1024;

  const int sr = (wid << 3) + (lane >> 3);
  const int sg = ((lane & 7) ^ ((lane >> 3) & 7)) << 3;
  bf16* pw = &Ps[wid][0];

  {
    gload_lds16(kbase + (size_t)sr * 64 + sg,          &Ks[0][wid * 512]);
    gload_lds16(kbase + (size_t)(sr + 32) * 64 + sg,   &Ks[0][2048 + wid * 512]);
    gload_lds16(vbase + (size_t)sr * 1024 + sg,        &Vs[0][wid * 512]);
    gload_lds16(vbase + (size_t)(sr + 32) * 1024 + sg, &Vs[0][2048 + wid * 512]);
  }

  int cur = 0;
  for (int kt = 0; kt < nkt; ++kt) {
    __syncthreads();
    if (kt + 1 < nkt) {
      const int tk0 = (kt + 1) << 6;
      const int nb = cur ^ 1;
      gload_lds16(kbase + (size_t)(tk0 + sr) * 64 + sg,        &Ks[nb][wid * 512]);
      gload_lds16(kbase + (size_t)(tk0 + sr + 32) * 64 + sg,   &Ks[nb][2048 + wid * 512]);
      gload_lds16(vbase + (size_t)sr * 1024 + tk0 + sg,        &Vs[nb][wid * 512]);
      gload_lds16(vbase + (size_t)(sr + 32) * 1024 + tk0 + sg, &Vs[nb][2048 + wid * 512]);
    }

    f32x4 sa[4] = {};
#pragma unroll
    for (int nf = 0; nf < 4; ++nf) {
      const int row = nf * 16 + ml;
#pragma unroll
      for (int ks = 0; ks < 2; ++ks) {
        const int g = ((ks * 4 + hi) ^ (ml & 7)) << 3;
        bf16x8 bk = *(const bf16x8*)&Ks[cur][row * 64 + g];
        sa[nf] = __builtin_amdgcn_mfma_f32_16x16x32_bf16(aq[ks], bk, sa[nf], 0, 0, 0);
      }
    }

#pragma unroll
    for (int nf = 0; nf < 4; ++nf) {
      const int gp0 = nf * 2 + (ml >> 3);
#pragma unroll
      for (int j = 0; j < 4; ++j) {
        const float p = __expf(sa[nf][j] * 0.125f);
        lsum[j] += p;
        const int prow = (hi << 2) + j;
        pw[prow * 64 + ((gp0 ^ (prow & 7)) << 3) + (ml & 7)] = (bf16)p;
      }
    }

#pragma unroll
    for (int ks = 0; ks < 2; ++ks) {
      const int g = ((ks * 4 + hi) ^ (ml & 7)) << 3;
      bf16x8 pa = *(const bf16x8*)&pw[ml * 64 + g];
#pragma unroll
      for (int df = 0; df < 4; ++df) {
        bf16x8 bv = *(const bf16x8*)&Vs[cur][(df * 16 + ml) * 64 + g];
        accO[df] = __builtin_amdgcn_mfma_f32_16x16x32_bf16(pa, bv, accO[df], 0, 0, 0);
      }
    }
    cur ^= 1;
  }

  float inv[4];
#pragma unroll
  for (int j = 0; j < 4; ++j) {
    float s = lsum[j];
#pragma unroll
    for (int off = 1; off < 16; off <<= 1) s += __shfl_xor(s, off);
    inv[j] = 1.f / s;
  }
#pragma unroll
  for (int df = 0; df < 4; ++df)
#pragma unroll
    for (int j = 0; j < 4; ++j) {
      const int t = t0 + wid * 16 + (hi << 2) + j;
      const int c = h * 64 + df * 16 + ml;
      y[((size_t)b * 1024 + t) * 512 + c] = (bf16)(accO[df][j] * inv[j]);
    }
}

// ---------------------------------------------------------------------------
extern "C" void kernel_launch(void* const* d_in, const int* in_sizes, int n_in,
                              void* d_out, int out_size, void* d_ws, size_t ws_size,
                              hipStream_t stream)
{
  const float* xi    = (const float*)d_in[0];
  const float* xc    = (const float*)d_in[1];
  const float* xj    = (const float*)d_in[2];
  const float* ln1_g = (const float*)d_in[3];
  const float* ln1_b = (const float*)d_in[4];
  const float* ln2_g = (const float*)d_in[5];
  const float* ln2_b = (const float*)d_in[6];
  const float* Wq    = (const float*)d_in[7];
  const float* bq    = (const float*)d_in[8];
  const float* Wkv   = (const float*)d_in[9];
  const float* bkv   = (const float*)d_in[10];
  const float* Wo    = (const float*)d_in[11];
  const float* bo    = (const float*)d_in[12];
  const float* Wfc   = (const float*)d_in[13];
  const float* bfc   = (const float*)d_in[14];
  const float* Wpr   = (const float*)d_in[15];
  const float* bpr   = (const float*)d_in[16];

  char* ws = (char*)d_ws;
  const size_t MB = 1ull << 20;
  bf16*  qs    = (bf16*)(ws + 0);
  bf16*  kvs   = (bf16*)(ws + 8 * MB);
  float* cs0   = (float*)(ws + 16 * MB);
  bf16*  WqT   = (bf16*)(ws + 32 * MB);
  bf16*  WkvT  = (bf16*)(ws + 32 * MB + 512 * 1024);
  bf16*  WoT   = (bf16*)(ws + 33 * MB + 512 * 1024);
  bf16*  WfcT  = (bf16*)(ws + 34 * MB);
  bf16*  WprT  = (bf16*)(ws + 36 * MB);
  bf16*  q_buf = (bf16*)(ws + 38 * MB);
  bf16*  k_buf = (bf16*)(ws + 46 * MB);
  bf16*  v_t   = (bf16*)(ws + 54 * MB);
  bf16*  yb    = (bf16*)(ws + 0);
  bf16*  hcs   = (bf16*)(ws + 8 * MB);
  bf16*  fcact = (bf16*)(ws + 38 * MB);
  float* cs    = cs0;

  prep_k<<<dim3(4608), 256, 0, stream>>>(Wq, Wkv, Wo, Wfc, Wpr,
                                         WqT, WkvT, WoT, WfcT, WprT,
                                         xi, xj, xc, ln1_g, ln1_b, qs, kvs, cs0);

  gemm_qkv_k<<<dim3(64, 12), 256, 0, stream>>>(qs, kvs, WqT, WkvT, bq, bkv,
                                               q_buf, k_buf, v_t);

  attn_k<<<dim3(1024), 256, 0, stream>>>(q_buf, k_buf, v_t, yb);

  gemmsk_k<EPI_O><<<dim3(64, 4), 512, 0, stream>>>(yb, WoT, bo, cs0,
                                                   (void*)cs, 512);

  ln2_k<<<dim3(2048), 256, 0, stream>>>(cs, ln2_g, ln2_b, hcs);

  gemm_fc_k<<<dim3(64, 16), 256, 0, stream>>>(hcs, WfcT, bfc, fcact);

  gemmsk_k<EPI_PR><<<dim3(64, 4), 512, 0, stream>>>(fcact, WprT, bpr, cs,
                                                    d_out, 2048);

  (void)in_sizes; (void)n_in; (void)out_size; (void)ws_size;
}

// Round 6
// 184.189 us; speedup vs baseline: 1.0435x; 1.0435x over previous
//
#include <hip/hip_runtime.h>
#include <hip/hip_bf16.h>
#include <math.h>

// ---------------------------------------------------------------------------
// CrossCausalAttentionBlock on MI355X (gfx950)
// B=8, T=1024 (V=4 blocks of 256), C=512, NH=8, hd=64
// R6: prep LN phase-2 read g/bb from LDS (was 64 in-loop global loads per
//     thread on the dependent chain -> latency-bound at 2.3 TB/s).
// ---------------------------------------------------------------------------

typedef __bf16 bf16;
typedef __bf16 bf16x8 __attribute__((ext_vector_type(8)));
typedef __bf16 bf16x4 __attribute__((ext_vector_type(4)));
typedef float  f32x4  __attribute__((ext_vector_type(4)));

__device__ __forceinline__ void gload_lds16(const void* g, void* l) {
  __builtin_amdgcn_global_load_lds(
      (__attribute__((address_space(1))) void*)(g),
      (__attribute__((address_space(3))) void*)(l), 16, 0, 0);
}

// ---------------------------------------------------------------------------
// Kernel 1: prep = all weight converts (blocks 0..3071) + gather+LN1 (3072..4607)
// ---------------------------------------------------------------------------
__global__ __launch_bounds__(256)
void prep_k(const float* __restrict__ Wq, const float* __restrict__ Wkv,
            const float* __restrict__ Wo, const float* __restrict__ Wfc,
            const float* __restrict__ Wpr,
            bf16* __restrict__ WqT, bf16* __restrict__ WkvT,
            bf16* __restrict__ WoT, bf16* __restrict__ WfcT,
            bf16* __restrict__ WprT,
            const float* __restrict__ xi, const float* __restrict__ xj,
            const float* __restrict__ xc,
            const float* __restrict__ g, const float* __restrict__ bb,
            bf16* __restrict__ qs, bf16* __restrict__ kvs,
            float* __restrict__ cs0)
{
  __shared__ __align__(16) float smemf[512 * 17]; // 34816 B
  __shared__ __align__(16) float gv[512];         // ln1 gamma (LDS-staged)
  __shared__ __align__(16) float bv[512];         // ln1 beta
  const int t = blockIdx.x;
  const int tid = threadIdx.x;
  if (t < 3072) { // ---- weight transpose-convert, 32x32 tiles
    const float* W; bf16* Wt; int K, N, lognx, tl;
    if (t < 256)       { W = Wq;  Wt = WqT;  K = 512;  N = 512;  lognx = 4; tl = t; }
    else if (t < 768)  { W = Wkv; Wt = WkvT; K = 512;  N = 1024; lognx = 5; tl = t - 256; }
    else if (t < 1024) { W = Wo;  Wt = WoT;  K = 512;  N = 512;  lognx = 4; tl = t - 768; }
    else if (t < 2048) { W = Wfc; Wt = WfcT; K = 512;  N = 2048; lognx = 6; tl = t - 1024; }
    else               { W = Wpr; Wt = WprT; K = 2048; N = 512;  lognx = 4; tl = t - 2048; }
    const int bx = tl & ((1 << lognx) - 1), by = tl >> lognx;
    float (*tt)[33] = (float (*)[33])smemf;
    const int x = tid & 31, y = tid >> 5;
    const int n0 = bx << 5, k0 = by << 5;
#pragma unroll
    for (int yy = y; yy < 32; yy += 8)
      tt[yy][x] = W[(size_t)(k0 + yy) * N + n0 + x];
    __syncthreads();
#pragma unroll
    for (int yy = y; yy < 32; yy += 8)
      Wt[(size_t)(n0 + yy) * K + k0 + x] = (bf16)tt[x][yy];
    return;
  }
  // ---- gather [v,b,c,h,w] -> [b,t,c] + LN1
  const int u = t - 3072;
  const int sel = u >> 9, bid = u & 511;
  const int hh = bid & 15, b = (bid >> 4) & 7, v = bid >> 7;
  const float* src = (sel == 0) ? xi : ((sel == 1) ? xj : xc);
  const size_t base = ((size_t)(v * 8 + b) * 512) * 256 + (size_t)hh * 16;
  float* tile = smemf;
  // stage gamma/beta to LDS (one f32x4 per thread)
  if (tid < 128)
    *(f32x4*)&gv[tid * 4] = *(const f32x4*)&g[tid * 4];
  else
    *(f32x4*)&bv[(tid - 128) * 4] = *(const f32x4*)&bb[(tid - 128) * 4];
  { // phase 1: float4 vectorized gather. thread = (chb = tid>>2, w4 = tid&3)
    const int w4 = (tid & 3) << 2, chb = tid >> 2;
#pragma unroll
    for (int k = 0; k < 8; ++k) {
      const int ch = chb + (k << 6);
      const f32x4 vv = *(const f32x4*)&src[base + (size_t)ch * 256 + w4];
#pragma unroll
      for (int i = 0; i < 4; ++i)
        tile[ch * 17 + w4 + i] = vv[i];
    }
  }
  __syncthreads();
  const int w2 = tid >> 4, cg2 = tid & 15;
  float s = 0.f, ss = 0.f;
#pragma unroll
  for (int k = 0; k < 32; ++k) {
    float x = tile[(cg2 + (k << 4)) * 17 + w2];
    s += x; ss += x * x;
  }
#pragma unroll
  for (int off = 1; off < 16; off <<= 1) {
    s += __shfl_xor(s, off);
    ss += __shfl_xor(ss, off);
  }
  const float mu = s * (1.f / 512.f);
  const float rstd = rsqrtf(ss * (1.f / 512.f) - mu * mu + 1e-5f);
  const int tk = v * 256 + hh * 16 + w2;
  const size_t orow = ((size_t)b * 1024 + tk) * 512;
#pragma unroll
  for (int k = 0; k < 32; ++k) {
    int ch = cg2 + (k << 4);
    float x = (tile[ch * 17 + w2] - mu) * rstd * gv[ch] + bv[ch];
    if (sel == 0)      qs[orow + ch]  = (bf16)x;
    else if (sel == 1) kvs[orow + ch] = (bf16)x;
    else               cs0[orow + ch] = x;
  }
}

// ---------------------------------------------------------------------------
// Kernel 3: row LayerNorm(ln2) on cs f32[8192][512] -> hcs bf16. 1 wave/row.
// ---------------------------------------------------------------------------
__global__ __launch_bounds__(256)
void ln2_k(const float* __restrict__ cs, const float* __restrict__ g,
           const float* __restrict__ bb, bf16* __restrict__ hcs)
{
  const int tid = threadIdx.x, wid = tid >> 6, lane = tid & 63;
  const int row = blockIdx.x * 4 + wid;
  const float* x = cs + (size_t)row * 512 + lane * 8;
  float v[8];
  *(f32x4*)&v[0] = *(const f32x4*)&x[0];
  *(f32x4*)&v[4] = *(const f32x4*)&x[4];
  float s = 0.f, ss = 0.f;
#pragma unroll
  for (int k = 0; k < 8; ++k) { s += v[k]; ss += v[k] * v[k]; }
#pragma unroll
  for (int off = 1; off < 64; off <<= 1) {
    s += __shfl_xor(s, off);
    ss += __shfl_xor(ss, off);
  }
  const float mu = s * (1.f / 512.f);
  const float rstd = rsqrtf(ss * (1.f / 512.f) - mu * mu + 1e-5f);
  bf16x8 o;
#pragma unroll
  for (int k = 0; k < 8; ++k) {
    int ch = lane * 8 + k;
    o[k] = (bf16)((v[k] - mu) * rstd * g[ch] + bb[ch]);
  }
  *(bf16x8*)&hcs[(size_t)row * 512 + lane * 8] = o;
}

// ---------------------------------------------------------------------------
// Kernel 4: FC GEMM (M=8192, N=2048, K=512), 2-phase dbuf, GELU epilogue
// staged through padded LDS (stride 132) for full-line coalesced stores.
// ---------------------------------------------------------------------------
__global__ __launch_bounds__(256)
void gemm_fc_k(const bf16* __restrict__ A, const bf16* __restrict__ Bt,
               const float* __restrict__ bias, bf16* __restrict__ fo)
{
  const int K = 512;
  __shared__ __align__(16) char smem[34816];
  bf16* As = (bf16*)smem;            // [2][4096]
  bf16* Bs = (bf16*)(smem + 16384);  // [2][4096]
  const int tid = threadIdx.x;
  const int wid = tid >> 6, lane = tid & 63;
  const int wr = wid >> 1, wc = wid & 1;
  const int ml = lane & 15, kg = (lane >> 4) << 3;
  const int m0 = blockIdx.x * 128, n0 = blockIdx.y * 128;

  const int e0 = wid * 512 + lane * 8;
  const int r0 = e0 >> 5, c0 = e0 & 31;
  const int e1 = e0 + 2048;
  const int r1 = e1 >> 5, c1 = e1 & 31;

  const bf16* Ag = A + (size_t)m0 * K;
  const bf16* Bg = Bt + (size_t)n0 * K;

  f32x4 acc[4][4] = {};

  gload_lds16(Ag + (size_t)r0 * K + c0, As + wid * 512);
  gload_lds16(Ag + (size_t)r1 * K + c1, As + 2048 + wid * 512);
  gload_lds16(Bg + (size_t)r0 * K + c0, Bs + wid * 512);
  gload_lds16(Bg + (size_t)r1 * K + c1, Bs + 2048 + wid * 512);

  int cur = 0;
  for (int k0 = 0; k0 < K; k0 += 32) {
    __syncthreads();
    if (k0 + 32 < K) {
      const int nb = cur ^ 1, kn = k0 + 32;
      gload_lds16(Ag + (size_t)r0 * K + kn + c0, As + nb * 4096 + wid * 512);
      gload_lds16(Ag + (size_t)r1 * K + kn + c1, As + nb * 4096 + 2048 + wid * 512);
      gload_lds16(Bg + (size_t)r0 * K + kn + c0, Bs + nb * 4096 + wid * 512);
      gload_lds16(Bg + (size_t)r1 * K + kn + c1, Bs + nb * 4096 + 2048 + wid * 512);
    }
    bf16x8 af[4], bfr[4];
#pragma unroll
    for (int mf = 0; mf < 4; ++mf)
      af[mf] = *(const bf16x8*)&As[cur * 4096 + (wr * 64 + mf * 16 + ml) * 32 + kg];
#pragma unroll
    for (int nf = 0; nf < 4; ++nf)
      bfr[nf] = *(const bf16x8*)&Bs[cur * 4096 + (wc * 64 + nf * 16 + ml) * 32 + kg];
#pragma unroll
    for (int mf = 0; mf < 4; ++mf)
#pragma unroll
      for (int nf = 0; nf < 4; ++nf)
        acc[mf][nf] = __builtin_amdgcn_mfma_f32_16x16x32_bf16(
            af[mf], bfr[nf], acc[mf][nf], 0, 0, 0);
    cur ^= 1;
  }

  // GELU -> padded LDS tile (stride 132) -> coalesced 16B row stores
  __syncthreads();
  bf16* OT = (bf16*)smem; // [128][132]
  const int jrow0 = (lane >> 4) << 2;
#pragma unroll
  for (int nf = 0; nf < 4; ++nf) {
    const float bv = bias[n0 + wc * 64 + nf * 16 + ml];
#pragma unroll
    for (int mf = 0; mf < 4; ++mf)
#pragma unroll
      for (int j = 0; j < 4; ++j) {
        float x = acc[mf][nf][j] + bv;
        float u = 0.7978845608f * (x + 0.044715f * x * x * x);
        float e = __expf(2.f * u);
        float th = 1.f - 2.f / (e + 1.f);
        OT[(wr * 64 + mf * 16 + jrow0 + j) * 132 + wc * 64 + nf * 16 + ml] =
            (bf16)(0.5f * x * (1.f + th));
      }
  }
  __syncthreads();
#pragma unroll
  for (int it = 0; it < 8; ++it) {
    const int idx = it * 256 + tid;
    const int cg = idx & 15, r = idx >> 4;
    *(bf16x8*)&fo[(size_t)(m0 + r) * 2048 + n0 + cg * 8] =
        *(const bf16x8*)&OT[r * 132 + cg * 8];
  }
}

// ---------------------------------------------------------------------------
// Kernel 4b: in-block split-K GEMM for N=512 stages (O, PR). 512 threads,
// 2 wave-groups x K-half, 2-phase dbuf each; LDS combine; group 1 epilogues.
// ---------------------------------------------------------------------------
enum { EPI_O = 2, EPI_PR = 4 };

template <int EPI>
__global__ __launch_bounds__(512)
void gemmsk_k(const bf16* __restrict__ A, const bf16* __restrict__ Bt,
              const float* __restrict__ bias, const float* res,
              void* out0, int K)
{
  __shared__ __align__(16) char smem[131072];
  bf16*  AS = (bf16*)smem;
  bf16*  BS = (bf16*)(smem + 65536);
  float* CF = (float*)smem;

  const int tid = threadIdx.x;
  const int wid = tid >> 6, lane = tid & 63;
  const int half = wid >> 2, w2 = wid & 3;
  const int wr = w2 >> 1, wc = w2 & 1;
  const int ml = lane & 15, kg = (lane >> 4) << 3;
  const int m0 = blockIdx.x * 128, n0 = blockIdx.y * 128;
  const int Kh = K >> 1;

  const int e0 = w2 * 512 + lane * 8;
  const int r0 = e0 >> 5, c0 = e0 & 31;
  const int e1 = e0 + 2048;
  const int r1 = e1 >> 5, c1 = e1 & 31;

  const bf16* Ag = A + (size_t)m0 * K + half * Kh;
  const bf16* Bg = Bt + (size_t)n0 * K + half * Kh;
  bf16* A0 = AS + half * 4096;
  bf16* B0 = BS + half * 4096;

  f32x4 acc[4][4] = {};

  gload_lds16(Ag + (size_t)r0 * K + c0, A0 + w2 * 512);
  gload_lds16(Ag + (size_t)r1 * K + c1, A0 + 2048 + w2 * 512);
  gload_lds16(Bg + (size_t)r0 * K + c0, B0 + w2 * 512);
  gload_lds16(Bg + (size_t)r1 * K + c1, B0 + 2048 + w2 * 512);

  int cur = 0;
  for (int k0 = 0; k0 < Kh; k0 += 32) {
    __syncthreads();
    if (k0 + 32 < Kh) {
      const int kn = k0 + 32;
      bf16* An = AS + ((cur ^ 1) * 8192) + half * 4096;
      bf16* Bn = BS + ((cur ^ 1) * 8192) + half * 4096;
      gload_lds16(Ag + (size_t)r0 * K + kn + c0, An + w2 * 512);
      gload_lds16(Ag + (size_t)r1 * K + kn + c1, An + 2048 + w2 * 512);
      gload_lds16(Bg + (size_t)r0 * K + kn + c0, Bn + w2 * 512);
      gload_lds16(Bg + (size_t)r1 * K + kn + c1, Bn + 2048 + w2 * 512);
    }
    const bf16* Ac = AS + cur * 8192 + half * 4096;
    const bf16* Bc = BS + cur * 8192 + half * 4096;
    bf16x8 af[4], bfr[4];
#pragma unroll
    for (int mf = 0; mf < 4; ++mf)
      af[mf] = *(const bf16x8*)&Ac[(wr * 64 + mf * 16 + ml) * 32 + kg];
#pragma unroll
    for (int nf = 0; nf < 4; ++nf)
      bfr[nf] = *(const bf16x8*)&Bc[(wc * 64 + nf * 16 + ml) * 32 + kg];
#pragma unroll
    for (int mf = 0; mf < 4; ++mf)
#pragma unroll
      for (int nf = 0; nf < 4; ++nf)
        acc[mf][nf] = __builtin_amdgcn_mfma_f32_16x16x32_bf16(
            af[mf], bfr[nf], acc[mf][nf], 0, 0, 0);
    cur ^= 1;
  }

  const int jrow0 = (lane >> 4) << 2;
  __syncthreads();
  if (half == 0) {
#pragma unroll
    for (int mf = 0; mf < 4; ++mf)
#pragma unroll
      for (int nf = 0; nf < 4; ++nf)
#pragma unroll
        for (int j = 0; j < 4; ++j)
          CF[(wr * 64 + mf * 16 + jrow0 + j) * 128 + wc * 64 + nf * 16 + ml] =
              acc[mf][nf][j];
  }
  __syncthreads();
  if (half == 1) {
#pragma unroll
    for (int nf = 0; nf < 4; ++nf) {
      const int n = n0 + wc * 64 + nf * 16 + ml;
      const float bv = bias[n];
#pragma unroll
      for (int mf = 0; mf < 4; ++mf) {
        const int mbase = m0 + wr * 64 + mf * 16 + jrow0;
        float v4[4];
#pragma unroll
        for (int j = 0; j < 4; ++j)
          v4[j] = acc[mf][nf][j] +
                  CF[(wr * 64 + mf * 16 + jrow0 + j) * 128 + wc * 64 + nf * 16 + ml];
        if constexpr (EPI == EPI_O) {
          float* cs = (float*)out0;
#pragma unroll
          for (int j = 0; j < 4; ++j) {
            const size_t idx = (size_t)(mbase + j) * 512 + n;
            cs[idx] = v4[j] + bv + res[idx];
          }
        } else {
          float* out = (float*)out0;
          const int b = mbase >> 10, t = mbase & 1023;
          const int v = t >> 8, hhh = (t >> 4) & 15, w0 = t & 15;
          f32x4 o;
#pragma unroll
          for (int j = 0; j < 4; ++j)
            o[j] = v4[j] + bv + res[(size_t)(mbase + j) * 512 + n];
          *(f32x4*)&out[(((size_t)v * 8 + b) * 512 + n) * 256 + hhh * 16 + w0] = o;
        }
      }
    }
  }
}

// ---------------------------------------------------------------------------
// Kernel 4c: merged Q + KV projection GEMM, 2-phase dbuf, LDS-staged stores.
// Grid (64, 12): ybl 0-3 Q, 4-7 K, 8-11 V(transposed).
// ---------------------------------------------------------------------------
__global__ __launch_bounds__(256)
void gemm_qkv_k(const bf16* __restrict__ Aq, const bf16* __restrict__ Akv,
                const bf16* __restrict__ WqT, const bf16* __restrict__ WkvT,
                const float* __restrict__ bq, const float* __restrict__ bkv,
                bf16* __restrict__ q_buf, bf16* __restrict__ k_buf,
                bf16* __restrict__ v_t)
{
  const int K = 512;
  __shared__ __align__(16) char smem[34816];
  bf16* As = (bf16*)smem;
  bf16* Bs = (bf16*)(smem + 16384);
  const int tid = threadIdx.x;
  const int wid = tid >> 6, lane = tid & 63;
  const int wr = wid >> 1, wc = wid & 1;
  const int ml = lane & 15, kg = (lane >> 4) << 3;
  const int ybl = blockIdx.y;
  const bool isq = ybl < 4;
  const bf16* A     = isq ? Aq  : Akv;
  const bf16* Bt    = isq ? WqT : WkvT;
  const float* bias = isq ? bq : bkv;
  const int n0 = isq ? (ybl << 7) : ((ybl - 4) << 7);
  const int m0 = blockIdx.x * 128;

  const int e0 = wid * 512 + lane * 8;
  const int r0 = e0 >> 5, c0 = e0 & 31;
  const int e1 = e0 + 2048;
  const int r1 = e1 >> 5, c1 = e1 & 31;

  const bf16* Ag = A + (size_t)m0 * K;
  const bf16* Bg = Bt + (size_t)n0 * K;

  f32x4 acc[4][4] = {};

  gload_lds16(Ag + (size_t)r0 * K + c0, As + wid * 512);
  gload_lds16(Ag + (size_t)r1 * K + c1, As + 2048 + wid * 512);
  gload_lds16(Bg + (size_t)r0 * K + c0, Bs + wid * 512);
  gload_lds16(Bg + (size_t)r1 * K + c1, Bs + 2048 + wid * 512);

  int cur = 0;
  for (int k0 = 0; k0 < K; k0 += 32) {
    __syncthreads();
    if (k0 + 32 < K) {
      const int nb = cur ^ 1, kn = k0 + 32;
      gload_lds16(Ag + (size_t)r0 * K + kn + c0, As + nb * 4096 + wid * 512);
      gload_lds16(Ag + (size_t)r1 * K + kn + c1, As + nb * 4096 + 2048 + wid * 512);
      gload_lds16(Bg + (size_t)r0 * K + kn + c0, Bs + nb * 4096 + wid * 512);
      gload_lds16(Bg + (size_t)r1 * K + kn + c1, Bs + nb * 4096 + 2048 + wid * 512);
    }
    bf16x8 af[4], bfr[4];
#pragma unroll
    for (int mf = 0; mf < 4; ++mf)
      af[mf] = *(const bf16x8*)&As[cur * 4096 + (wr * 64 + mf * 16 + ml) * 32 + kg];
#pragma unroll
    for (int nf = 0; nf < 4; ++nf)
      bfr[nf] = *(const bf16x8*)&Bs[cur * 4096 + (wc * 64 + nf * 16 + ml) * 32 + kg];
#pragma unroll
    for (int mf = 0; mf < 4; ++mf)
#pragma unroll
      for (int nf = 0; nf < 4; ++nf)
        acc[mf][nf] = __builtin_amdgcn_mfma_f32_16x16x32_bf16(
            af[mf], bfr[nf], acc[mf][nf], 0, 0, 0);
    cur ^= 1;
  }

  __syncthreads();
  bf16* OT = (bf16*)smem; // [128][132] padded
  const int jrow0 = (lane >> 4) << 2;
  const int b = m0 >> 10, t0 = m0 & 1023;
  if (ybl < 8) { // Q or K: stage row-major (row=m, col=n)
#pragma unroll
    for (int nf = 0; nf < 4; ++nf) {
      const float bv = bias[n0 + wc * 64 + nf * 16 + ml];
#pragma unroll
      for (int mf = 0; mf < 4; ++mf)
#pragma unroll
        for (int j = 0; j < 4; ++j)
          OT[(wr * 64 + mf * 16 + jrow0 + j) * 132 + wc * 64 + nf * 16 + ml] =
              (bf16)(acc[mf][nf][j] + bv);
    }
    __syncthreads();
    bf16* dst = isq ? q_buf : k_buf;
    const int h0 = n0 >> 6;
#pragma unroll
    for (int it = 0; it < 8; ++it) {
      const int idx = it * 256 + tid;
      const int dg = idx & 7, r = (idx >> 3) & 127, hl = idx >> 10;
      *(bf16x8*)&dst[(((size_t)b * 8 + h0 + hl) * 1024 + t0 + r) * 64 + dg * 8] =
          *(const bf16x8*)&OT[r * 132 + hl * 64 + dg * 8];
    }
  } else { // V: stage col-major (row=n col, col=m) for t-contiguous stores
#pragma unroll
    for (int nf = 0; nf < 4; ++nf) {
      const float bv = bias[n0 + wc * 64 + nf * 16 + ml];
#pragma unroll
      for (int mf = 0; mf < 4; ++mf) {
        bf16x4 o;
#pragma unroll
        for (int j = 0; j < 4; ++j) o[j] = (bf16)(acc[mf][nf][j] + bv);
        *(bf16x4*)&OT[(wc * 64 + nf * 16 + ml) * 132 + wr * 64 + mf * 16 + jrow0] = o;
      }
    }
    __syncthreads();
    const int h0 = (n0 - 512) >> 6;
#pragma unroll
    for (int it = 0; it < 8; ++it) {
      const int idx = it * 256 + tid;
      const int og = idx & 15, c = idx >> 4;
      const int hl = c >> 6, d = c & 63;
      *(bf16x8*)&v_t[(((size_t)b * 8 + h0 + hl) * 64 + d) * 1024 + t0 + og * 8] =
          *(const bf16x8*)&OT[c * 132 + og * 8];
    }
  }
}

// ---------------------------------------------------------------------------
// Kernel 5: block-causal flash attention (unchanged from R2-R5).
// ---------------------------------------------------------------------------
__global__ __launch_bounds__(256)
void attn_k(const bf16* __restrict__ qb, const bf16* __restrict__ kb,
            const bf16* __restrict__ vt, bf16* __restrict__ y)
{
  __shared__ bf16 Ks[2][4096];
  __shared__ bf16 Vs[2][4096];
  __shared__ bf16 Ps[4][1024];
  const int tid = threadIdx.x, wid = tid >> 6, lane = tid & 63;
  const int L = blockIdx.x;
  const int xcd = L & 7, chunk = L >> 3;
  const int bh = xcd + ((chunk >> 4) << 3);
  const int qt = 15 - (chunk & 15);
  const int b = bh >> 3, h = bh & 7;
  const int t0 = qt << 6;
  const int ml = lane & 15, hi = lane >> 4, kg = hi << 3;

  const bf16* qrow = qb + ((size_t)bh * 1024 + t0 + wid * 16) * 64;
  bf16x8 aq[2];
  aq[0] = *(const bf16x8*)&qrow[ml * 64 + kg];
  aq[1] = *(const bf16x8*)&qrow[ml * 64 + 32 + kg];

  f32x4 accO[4] = {};
  float lsum[4] = {0.f, 0.f, 0.f, 0.f};

  const int nkt = ((qt >> 2) + 1) << 2;
  const bf16* kbase = kb + (size_t)bh * 1024 * 64;
  const bf16* vbase = vt + (size_t)bh * 64 * 1024;

  const int sr = (wid << 3) + (lane >> 3);
  const int sg = ((lane & 7) ^ ((lane >> 3) & 7)) << 3;
  bf16* pw = &Ps[wid][0];

  {
    gload_lds16(kbase + (size_t)sr * 64 + sg,          &Ks[0][wid * 512]);
    gload_lds16(kbase + (size_t)(sr + 32) * 64 + sg,   &Ks[0][2048 + wid * 512]);
    gload_lds16(vbase + (size_t)sr * 1024 + sg,        &Vs[0][wid * 512]);
    gload_lds16(vbase + (size_t)(sr + 32) * 1024 + sg, &Vs[0][2048 + wid * 512]);
  }

  int cur = 0;
  for (int kt = 0; kt < nkt; ++kt) {
    __syncthreads();
    if (kt + 1 < nkt) {
      const int tk0 = (kt + 1) << 6;
      const int nb = cur ^ 1;
      gload_lds16(kbase + (size_t)(tk0 + sr) * 64 + sg,        &Ks[nb][wid * 512]);
      gload_lds16(kbase + (size_t)(tk0 + sr + 32) * 64 + sg,   &Ks[nb][2048 + wid * 512]);
      gload_lds16(vbase + (size_t)sr * 1024 + tk0 + sg,        &Vs[nb][wid * 512]);
      gload_lds16(vbase + (size_t)(sr + 32) * 1024 + tk0 + sg, &Vs[nb][2048 + wid * 512]);
    }

    f32x4 sa[4] = {};
#pragma unroll
    for (int nf = 0; nf < 4; ++nf) {
      const int row = nf * 16 + ml;
#pragma unroll
      for (int ks = 0; ks < 2; ++ks) {
        const int g = ((ks * 4 + hi) ^ (ml & 7)) << 3;
        bf16x8 bk = *(const bf16x8*)&Ks[cur][row * 64 + g];
        sa[nf] = __builtin_amdgcn_mfma_f32_16x16x32_bf16(aq[ks], bk, sa[nf], 0, 0, 0);
      }
    }

#pragma unroll
    for (int nf = 0; nf < 4; ++nf) {
      const int gp0 = nf * 2 + (ml >> 3);
#pragma unroll
      for (int j = 0; j < 4; ++j) {
        const float p = __expf(sa[nf][j] * 0.125f);
        lsum[j] += p;
        const int prow = (hi << 2) + j;
        pw[prow * 64 + ((gp0 ^ (prow & 7)) << 3) + (ml & 7)] = (bf16)p;
      }
    }

#pragma unroll
    for (int ks = 0; ks < 2; ++ks) {
      const int g = ((ks * 4 + hi) ^ (ml & 7)) << 3;
      bf16x8 pa = *(const bf16x8*)&pw[ml * 64 + g];
#pragma unroll
      for (int df = 0; df < 4; ++df) {
        bf16x8 bv = *(const bf16x8*)&Vs[cur][(df * 16 + ml) * 64 + g];
        accO[df] = __builtin_amdgcn_mfma_f32_16x16x32_bf16(pa, bv, accO[df], 0, 0, 0);
      }
    }
    cur ^= 1;
  }

  float inv[4];
#pragma unroll
  for (int j = 0; j < 4; ++j) {
    float s = lsum[j];
#pragma unroll
    for (int off = 1; off < 16; off <<= 1) s += __shfl_xor(s, off);
    inv[j] = 1.f / s;
  }
#pragma unroll
  for (int df = 0; df < 4; ++df)
#pragma unroll
    for (int j = 0; j < 4; ++j) {
      const int t = t0 + wid * 16 + (hi << 2) + j;
      const int c = h * 64 + df * 16 + ml;
      y[((size_t)b * 1024 + t) * 512 + c] = (bf16)(accO[df][j] * inv[j]);
    }
}

// ---------------------------------------------------------------------------
extern "C" void kernel_launch(void* const* d_in, const int* in_sizes, int n_in,
                              void* d_out, int out_size, void* d_ws, size_t ws_size,
                              hipStream_t stream)
{
  const float* xi    = (const float*)d_in[0];
  const float* xc    = (const float*)d_in[1];
  const float* xj    = (const float*)d_in[2];
  const float* ln1_g = (const float*)d_in[3];
  const float* ln1_b = (const float*)d_in[4];
  const float* ln2_g = (const float*)d_in[5];
  const float* ln2_b = (const float*)d_in[6];
  const float* Wq    = (const float*)d_in[7];
  const float* bq    = (const float*)d_in[8];
  const float* Wkv   = (const float*)d_in[9];
  const float* bkv   = (const float*)d_in[10];
  const float* Wo    = (const float*)d_in[11];
  const float* bo    = (const float*)d_in[12];
  const float* Wfc   = (const float*)d_in[13];
  const float* bfc   = (const float*)d_in[14];
  const float* Wpr   = (const float*)d_in[15];
  const float* bpr   = (const float*)d_in[16];

  char* ws = (char*)d_ws;
  const size_t MB = 1ull << 20;
  bf16*  qs    = (bf16*)(ws + 0);
  bf16*  kvs   = (bf16*)(ws + 8 * MB);
  float* cs0   = (float*)(ws + 16 * MB);
  bf16*  WqT   = (bf16*)(ws + 32 * MB);
  bf16*  WkvT  = (bf16*)(ws + 32 * MB + 512 * 1024);
  bf16*  WoT   = (bf16*)(ws + 33 * MB + 512 * 1024);
  bf16*  WfcT  = (bf16*)(ws + 34 * MB);
  bf16*  WprT  = (bf16*)(ws + 36 * MB);
  bf16*  q_buf = (bf16*)(ws + 38 * MB);
  bf16*  k_buf = (bf16*)(ws + 46 * MB);
  bf16*  v_t   = (bf16*)(ws + 54 * MB);
  bf16*  yb    = (bf16*)(ws + 0);
  bf16*  hcs   = (bf16*)(ws + 8 * MB);
  bf16*  fcact = (bf16*)(ws + 38 * MB);
  float* cs    = cs0;

  prep_k<<<dim3(4608), 256, 0, stream>>>(Wq, Wkv, Wo, Wfc, Wpr,
                                         WqT, WkvT, WoT, WfcT, WprT,
                                         xi, xj, xc, ln1_g, ln1_b, qs, kvs, cs0);

  gemm_qkv_k<<<dim3(64, 12), 256, 0, stream>>>(qs, kvs, WqT, WkvT, bq, bkv,
                                               q_buf, k_buf, v_t);

  attn_k<<<dim3(1024), 256, 0, stream>>>(q_buf, k_buf, v_t, yb);

  gemmsk_k<EPI_O><<<dim3(64, 4), 512, 0, stream>>>(yb, WoT, bo, cs0,
                                                   (void*)cs, 512);

  ln2_k<<<dim3(2048), 256, 0, stream>>>(cs, ln2_g, ln2_b, hcs);

  gemm_fc_k<<<dim3(64, 16), 256, 0, stream>>>(hcs, WfcT, bfc, fcact);

  gemmsk_k<EPI_PR><<<dim3(64, 4), 512, 0, stream>>>(fcact, WprT, bpr, cs,
                                                    d_out, 2048);

  (void)in_sizes; (void)n_in; (void)out_size; (void)ws_size;
}

// Round 7
// 182.475 us; speedup vs baseline: 1.0533x; 1.0094x over previous
//
#include <hip/hip_runtime.h>
#include <hip/hip_bf16.h>
#include <math.h>

// ---------------------------------------------------------------------------
// CrossCausalAttentionBlock on MI355X (gfx950)
// B=8, T=1024 (V=4 blocks of 256), C=512, NH=8, hd=64
// R7: prep LN path fully register-resident (was ~96 scalar LDS ops/thread,
//     LDS-issue-bound). Stats via shfl_xor(4/8/16/32) + 512B cross-wave LDS.
// ---------------------------------------------------------------------------

typedef __bf16 bf16;
typedef __bf16 bf16x8 __attribute__((ext_vector_type(8)));
typedef __bf16 bf16x4 __attribute__((ext_vector_type(4)));
typedef float  f32x4  __attribute__((ext_vector_type(4)));

__device__ __forceinline__ void gload_lds16(const void* g, void* l) {
  __builtin_amdgcn_global_load_lds(
      (__attribute__((address_space(1))) void*)(g),
      (__attribute__((address_space(3))) void*)(l), 16, 0, 0);
}

// ---------------------------------------------------------------------------
// Kernel 1: prep = weight converts (blocks 0..3071) + gather+LN1 (3072..4607)
// ---------------------------------------------------------------------------
__global__ __launch_bounds__(256)
void prep_k(const float* __restrict__ Wq, const float* __restrict__ Wkv,
            const float* __restrict__ Wo, const float* __restrict__ Wfc,
            const float* __restrict__ Wpr,
            bf16* __restrict__ WqT, bf16* __restrict__ WkvT,
            bf16* __restrict__ WoT, bf16* __restrict__ WfcT,
            bf16* __restrict__ WprT,
            const float* __restrict__ xi, const float* __restrict__ xj,
            const float* __restrict__ xc,
            const float* __restrict__ g, const float* __restrict__ bb,
            bf16* __restrict__ qs, bf16* __restrict__ kvs,
            float* __restrict__ cs0)
{
  __shared__ float tt[32][33];   // weight-transpose tile (4.2 KB)
  __shared__ float red[4][32];   // LN cross-wave reduce (512 B)
  const int t = blockIdx.x;
  const int tid = threadIdx.x;
  if (t < 3072) { // ---- weight transpose-convert, 32x32 tiles (unchanged)
    const float* W; bf16* Wt; int K, N, lognx, tl;
    if (t < 256)       { W = Wq;  Wt = WqT;  K = 512;  N = 512;  lognx = 4; tl = t; }
    else if (t < 768)  { W = Wkv; Wt = WkvT; K = 512;  N = 1024; lognx = 5; tl = t - 256; }
    else if (t < 1024) { W = Wo;  Wt = WoT;  K = 512;  N = 512;  lognx = 4; tl = t - 768; }
    else if (t < 2048) { W = Wfc; Wt = WfcT; K = 512;  N = 2048; lognx = 6; tl = t - 1024; }
    else               { W = Wpr; Wt = WprT; K = 2048; N = 512;  lognx = 4; tl = t - 2048; }
    const int bx = tl & ((1 << lognx) - 1), by = tl >> lognx;
    const int x = tid & 31, y = tid >> 5;
    const int n0 = bx << 5, k0 = by << 5;
#pragma unroll
    for (int yy = y; yy < 32; yy += 8)
      tt[yy][x] = W[(size_t)(k0 + yy) * N + n0 + x];
    __syncthreads();
#pragma unroll
    for (int yy = y; yy < 32; yy += 8)
      Wt[(size_t)(n0 + yy) * K + k0 + x] = (bf16)tt[x][yy];
    return;
  }
  // ---- gather [v,b,c,h,w] -> [b,t,c] + LN1, register-resident
  const int u = t - 3072;
  const int sel = u >> 9, bid = u & 511;
  const int hh = bid & 15, b = (bid >> 4) & 7, v = bid >> 7;
  const float* src = (sel == 0) ? xi : ((sel == 1) ? xj : xc);
  const size_t base = ((size_t)(v * 8 + b) * 512) * 256 + (size_t)hh * 16;
  const int q = tid & 3, chb = tid >> 2;       // w-quad q, channel chb(+64k)
  const int wid = tid >> 6, lane = tid & 63;

  // prefetch gamma/beta for this thread's 8 channels (L2-hot, off chain)
  float gr[8], br[8];
#pragma unroll
  for (int k = 0; k < 8; ++k) {
    gr[k] = g[chb + (k << 6)];
    br[k] = bb[chb + (k << 6)];
  }
  // load 8 ch x 4 tokens into registers (f32x4, 16B aligned)
  f32x4 x[8];
#pragma unroll
  for (int k = 0; k < 8; ++k)
    x[k] = *(const f32x4*)&src[base + (size_t)(chb + (k << 6)) * 256 + (q << 2)];

  // per-token partial stats over this thread's 8 channels
  float s[4] = {0.f, 0.f, 0.f, 0.f}, ss[4] = {0.f, 0.f, 0.f, 0.f};
#pragma unroll
  for (int k = 0; k < 8; ++k)
#pragma unroll
    for (int i = 0; i < 4; ++i) {
      s[i] += x[k][i];
      ss[i] += x[k][i] * x[k][i];
    }
  // reduce across the 16 same-q lanes of this wave (offsets preserve q-class)
#pragma unroll
  for (int off = 4; off < 64; off <<= 1)
#pragma unroll
    for (int i = 0; i < 4; ++i) {
      s[i] += __shfl_xor(s[i], off);
      ss[i] += __shfl_xor(ss[i], off);
    }
  // cross-wave combine via 512B LDS (entry e = q*4+i)
  if (lane < 16) {
    red[wid][(lane & 3) * 4 + (lane >> 2)]      = s[lane >> 2];
    red[wid][16 + (lane & 3) * 4 + (lane >> 2)] = ss[lane >> 2];
  }
  __syncthreads();
  float mu[4], rs[4];
#pragma unroll
  for (int i = 0; i < 4; ++i) {
    const int e = q * 4 + i;
    float st  = red[0][e] + red[1][e] + red[2][e] + red[3][e];
    float sst = red[0][16 + e] + red[1][16 + e] + red[2][16 + e] + red[3][16 + e];
    mu[i] = st * (1.f / 512.f);
    rs[i] = rsqrtf(sst * (1.f / 512.f) - mu[i] * mu[i] + 1e-5f);
  }
  // normalize from registers + store (16-consecutive-ch per token per instr)
  const int tkb = v * 256 + hh * 16 + (q << 2);
#pragma unroll
  for (int i = 0; i < 4; ++i) {
    const size_t orow = ((size_t)b * 1024 + tkb + i) * 512;
#pragma unroll
    for (int k = 0; k < 8; ++k) {
      const float y = (x[k][i] - mu[i]) * rs[i] * gr[k] + br[k];
      const int ch = chb + (k << 6);
      if (sel == 0)      qs[orow + ch]  = (bf16)y;
      else if (sel == 1) kvs[orow + ch] = (bf16)y;
      else               cs0[orow + ch] = y;
    }
  }
}

// ---------------------------------------------------------------------------
// Kernel 3: row LayerNorm(ln2) on cs f32[8192][512] -> hcs bf16. 1 wave/row.
// ---------------------------------------------------------------------------
__global__ __launch_bounds__(256)
void ln2_k(const float* __restrict__ cs, const float* __restrict__ g,
           const float* __restrict__ bb, bf16* __restrict__ hcs)
{
  const int tid = threadIdx.x, wid = tid >> 6, lane = tid & 63;
  const int row = blockIdx.x * 4 + wid;
  const float* x = cs + (size_t)row * 512 + lane * 8;
  float v[8];
  *(f32x4*)&v[0] = *(const f32x4*)&x[0];
  *(f32x4*)&v[4] = *(const f32x4*)&x[4];
  float s = 0.f, ss = 0.f;
#pragma unroll
  for (int k = 0; k < 8; ++k) { s += v[k]; ss += v[k] * v[k]; }
#pragma unroll
  for (int off = 1; off < 64; off <<= 1) {
    s += __shfl_xor(s, off);
    ss += __shfl_xor(ss, off);
  }
  const float mu = s * (1.f / 512.f);
  const float rstd = rsqrtf(ss * (1.f / 512.f) - mu * mu + 1e-5f);
  bf16x8 o;
#pragma unroll
  for (int k = 0; k < 8; ++k) {
    int ch = lane * 8 + k;
    o[k] = (bf16)((v[k] - mu) * rstd * g[ch] + bb[ch]);
  }
  *(bf16x8*)&hcs[(size_t)row * 512 + lane * 8] = o;
}

// ---------------------------------------------------------------------------
// Kernel 4: FC GEMM (M=8192, N=2048, K=512), 2-phase dbuf, GELU epilogue
// staged through padded LDS (stride 132) for full-line coalesced stores.
// ---------------------------------------------------------------------------
__global__ __launch_bounds__(256)
void gemm_fc_k(const bf16* __restrict__ A, const bf16* __restrict__ Bt,
               const float* __restrict__ bias, bf16* __restrict__ fo)
{
  const int K = 512;
  __shared__ __align__(16) char smem[34816];
  bf16* As = (bf16*)smem;            // [2][4096]
  bf16* Bs = (bf16*)(smem + 16384);  // [2][4096]
  const int tid = threadIdx.x;
  const int wid = tid >> 6, lane = tid & 63;
  const int wr = wid >> 1, wc = wid & 1;
  const int ml = lane & 15, kg = (lane >> 4) << 3;
  const int m0 = blockIdx.x * 128, n0 = blockIdx.y * 128;

  const int e0 = wid * 512 + lane * 8;
  const int r0 = e0 >> 5, c0 = e0 & 31;
  const int e1 = e0 + 2048;
  const int r1 = e1 >> 5, c1 = e1 & 31;

  const bf16* Ag = A + (size_t)m0 * K;
  const bf16* Bg = Bt + (size_t)n0 * K;

  f32x4 acc[4][4] = {};

  gload_lds16(Ag + (size_t)r0 * K + c0, As + wid * 512);
  gload_lds16(Ag + (size_t)r1 * K + c1, As + 2048 + wid * 512);
  gload_lds16(Bg + (size_t)r0 * K + c0, Bs + wid * 512);
  gload_lds16(Bg + (size_t)r1 * K + c1, Bs + 2048 + wid * 512);

  int cur = 0;
  for (int k0 = 0; k0 < K; k0 += 32) {
    __syncthreads();
    if (k0 + 32 < K) {
      const int nb = cur ^ 1, kn = k0 + 32;
      gload_lds16(Ag + (size_t)r0 * K + kn + c0, As + nb * 4096 + wid * 512);
      gload_lds16(Ag + (size_t)r1 * K + kn + c1, As + nb * 4096 + 2048 + wid * 512);
      gload_lds16(Bg + (size_t)r0 * K + kn + c0, Bs + nb * 4096 + wid * 512);
      gload_lds16(Bg + (size_t)r1 * K + kn + c1, Bs + nb * 4096 + 2048 + wid * 512);
    }
    bf16x8 af[4], bfr[4];
#pragma unroll
    for (int mf = 0; mf < 4; ++mf)
      af[mf] = *(const bf16x8*)&As[cur * 4096 + (wr * 64 + mf * 16 + ml) * 32 + kg];
#pragma unroll
    for (int nf = 0; nf < 4; ++nf)
      bfr[nf] = *(const bf16x8*)&Bs[cur * 4096 + (wc * 64 + nf * 16 + ml) * 32 + kg];
#pragma unroll
    for (int mf = 0; mf < 4; ++mf)
#pragma unroll
      for (int nf = 0; nf < 4; ++nf)
        acc[mf][nf] = __builtin_amdgcn_mfma_f32_16x16x32_bf16(
            af[mf], bfr[nf], acc[mf][nf], 0, 0, 0);
    cur ^= 1;
  }

  // GELU -> padded LDS tile (stride 132) -> coalesced 16B row stores
  __syncthreads();
  bf16* OT = (bf16*)smem; // [128][132]
  const int jrow0 = (lane >> 4) << 2;
#pragma unroll
  for (int nf = 0; nf < 4; ++nf) {
    const float bv = bias[n0 + wc * 64 + nf * 16 + ml];
#pragma unroll
    for (int mf = 0; mf < 4; ++mf)
#pragma unroll
      for (int j = 0; j < 4; ++j) {
        float x = acc[mf][nf][j] + bv;
        float u = 0.7978845608f * (x + 0.044715f * x * x * x);
        float e = __expf(2.f * u);
        float th = 1.f - 2.f / (e + 1.f);
        OT[(wr * 64 + mf * 16 + jrow0 + j) * 132 + wc * 64 + nf * 16 + ml] =
            (bf16)(0.5f * x * (1.f + th));
      }
  }
  __syncthreads();
#pragma unroll
  for (int it = 0; it < 8; ++it) {
    const int idx = it * 256 + tid;
    const int cg = idx & 15, r = idx >> 4;
    *(bf16x8*)&fo[(size_t)(m0 + r) * 2048 + n0 + cg * 8] =
        *(const bf16x8*)&OT[r * 132 + cg * 8];
  }
}

// ---------------------------------------------------------------------------
// Kernel 4b: in-block split-K GEMM for N=512 stages (O, PR). 512 threads,
// 2 wave-groups x K-half, 2-phase dbuf each; LDS combine; group 1 epilogues.
// ---------------------------------------------------------------------------
enum { EPI_O = 2, EPI_PR = 4 };

template <int EPI>
__global__ __launch_bounds__(512)
void gemmsk_k(const bf16* __restrict__ A, const bf16* __restrict__ Bt,
              const float* __restrict__ bias, const float* res,
              void* out0, int K)
{
  __shared__ __align__(16) char smem[131072];
  bf16*  AS = (bf16*)smem;
  bf16*  BS = (bf16*)(smem + 65536);
  float* CF = (float*)smem;

  const int tid = threadIdx.x;
  const int wid = tid >> 6, lane = tid & 63;
  const int half = wid >> 2, w2 = wid & 3;
  const int wr = w2 >> 1, wc = w2 & 1;
  const int ml = lane & 15, kg = (lane >> 4) << 3;
  const int m0 = blockIdx.x * 128, n0 = blockIdx.y * 128;
  const int Kh = K >> 1;

  const int e0 = w2 * 512 + lane * 8;
  const int r0 = e0 >> 5, c0 = e0 & 31;
  const int e1 = e0 + 2048;
  const int r1 = e1 >> 5, c1 = e1 & 31;

  const bf16* Ag = A + (size_t)m0 * K + half * Kh;
  const bf16* Bg = Bt + (size_t)n0 * K + half * Kh;
  bf16* A0 = AS + half * 4096;
  bf16* B0 = BS + half * 4096;

  f32x4 acc[4][4] = {};

  gload_lds16(Ag + (size_t)r0 * K + c0, A0 + w2 * 512);
  gload_lds16(Ag + (size_t)r1 * K + c1, A0 + 2048 + w2 * 512);
  gload_lds16(Bg + (size_t)r0 * K + c0, B0 + w2 * 512);
  gload_lds16(Bg + (size_t)r1 * K + c1, B0 + 2048 + w2 * 512);

  int cur = 0;
  for (int k0 = 0; k0 < Kh; k0 += 32) {
    __syncthreads();
    if (k0 + 32 < Kh) {
      const int kn = k0 + 32;
      bf16* An = AS + ((cur ^ 1) * 8192) + half * 4096;
      bf16* Bn = BS + ((cur ^ 1) * 8192) + half * 4096;
      gload_lds16(Ag + (size_t)r0 * K + kn + c0, An + w2 * 512);
      gload_lds16(Ag + (size_t)r1 * K + kn + c1, An + 2048 + w2 * 512);
      gload_lds16(Bg + (size_t)r0 * K + kn + c0, Bn + w2 * 512);
      gload_lds16(Bg + (size_t)r1 * K + kn + c1, Bn + 2048 + w2 * 512);
    }
    const bf16* Ac = AS + cur * 8192 + half * 4096;
    const bf16* Bc = BS + cur * 8192 + half * 4096;
    bf16x8 af[4], bfr[4];
#pragma unroll
    for (int mf = 0; mf < 4; ++mf)
      af[mf] = *(const bf16x8*)&Ac[(wr * 64 + mf * 16 + ml) * 32 + kg];
#pragma unroll
    for (int nf = 0; nf < 4; ++nf)
      bfr[nf] = *(const bf16x8*)&Bc[(wc * 64 + nf * 16 + ml) * 32 + kg];
#pragma unroll
    for (int mf = 0; mf < 4; ++mf)
#pragma unroll
      for (int nf = 0; nf < 4; ++nf)
        acc[mf][nf] = __builtin_amdgcn_mfma_f32_16x16x32_bf16(
            af[mf], bfr[nf], acc[mf][nf], 0, 0, 0);
    cur ^= 1;
  }

  const int jrow0 = (lane >> 4) << 2;
  __syncthreads();
  if (half == 0) {
#pragma unroll
    for (int mf = 0; mf < 4; ++mf)
#pragma unroll
      for (int nf = 0; nf < 4; ++nf)
#pragma unroll
        for (int j = 0; j < 4; ++j)
          CF[(wr * 64 + mf * 16 + jrow0 + j) * 128 + wc * 64 + nf * 16 + ml] =
              acc[mf][nf][j];
  }
  __syncthreads();
  if (half == 1) {
#pragma unroll
    for (int nf = 0; nf < 4; ++nf) {
      const int n = n0 + wc * 64 + nf * 16 + ml;
      const float bv = bias[n];
#pragma unroll
      for (int mf = 0; mf < 4; ++mf) {
        const int mbase = m0 + wr * 64 + mf * 16 + jrow0;
        float v4[4];
#pragma unroll
        for (int j = 0; j < 4; ++j)
          v4[j] = acc[mf][nf][j] +
                  CF[(wr * 64 + mf * 16 + jrow0 + j) * 128 + wc * 64 + nf * 16 + ml];
        if constexpr (EPI == EPI_O) {
          float* cs = (float*)out0;
#pragma unroll
          for (int j = 0; j < 4; ++j) {
            const size_t idx = (size_t)(mbase + j) * 512 + n;
            cs[idx] = v4[j] + bv + res[idx];
          }
        } else {
          float* out = (float*)out0;
          const int b = mbase >> 10, t = mbase & 1023;
          const int v = t >> 8, hhh = (t >> 4) & 15, w0 = t & 15;
          f32x4 o;
#pragma unroll
          for (int j = 0; j < 4; ++j)
            o[j] = v4[j] + bv + res[(size_t)(mbase + j) * 512 + n];
          *(f32x4*)&out[(((size_t)v * 8 + b) * 512 + n) * 256 + hhh * 16 + w0] = o;
        }
      }
    }
  }
}

// ---------------------------------------------------------------------------
// Kernel 4c: merged Q + KV projection GEMM, 2-phase dbuf, LDS-staged stores.
// Grid (64, 12): ybl 0-3 Q, 4-7 K, 8-11 V(transposed).
// ---------------------------------------------------------------------------
__global__ __launch_bounds__(256)
void gemm_qkv_k(const bf16* __restrict__ Aq, const bf16* __restrict__ Akv,
                const bf16* __restrict__ WqT, const bf16* __restrict__ WkvT,
                const float* __restrict__ bq, const float* __restrict__ bkv,
                bf16* __restrict__ q_buf, bf16* __restrict__ k_buf,
                bf16* __restrict__ v_t)
{
  const int K = 512;
  __shared__ __align__(16) char smem[34816];
  bf16* As = (bf16*)smem;
  bf16* Bs = (bf16*)(smem + 16384);
  const int tid = threadIdx.x;
  const int wid = tid >> 6, lane = tid & 63;
  const int wr = wid >> 1, wc = wid & 1;
  const int ml = lane & 15, kg = (lane >> 4) << 3;
  const int ybl = blockIdx.y;
  const bool isq = ybl < 4;
  const bf16* A     = isq ? Aq  : Akv;
  const bf16* Bt    = isq ? WqT : WkvT;
  const float* bias = isq ? bq : bkv;
  const int n0 = isq ? (ybl << 7) : ((ybl - 4) << 7);
  const int m0 = blockIdx.x * 128;

  const int e0 = wid * 512 + lane * 8;
  const int r0 = e0 >> 5, c0 = e0 & 31;
  const int e1 = e0 + 2048;
  const int r1 = e1 >> 5, c1 = e1 & 31;

  const bf16* Ag = A + (size_t)m0 * K;
  const bf16* Bg = Bt + (size_t)n0 * K;

  f32x4 acc[4][4] = {};

  gload_lds16(Ag + (size_t)r0 * K + c0, As + wid * 512);
  gload_lds16(Ag + (size_t)r1 * K + c1, As + 2048 + wid * 512);
  gload_lds16(Bg + (size_t)r0 * K + c0, Bs + wid * 512);
  gload_lds16(Bg + (size_t)r1 * K + c1, Bs + 2048 + wid * 512);

  int cur = 0;
  for (int k0 = 0; k0 < K; k0 += 32) {
    __syncthreads();
    if (k0 + 32 < K) {
      const int nb = cur ^ 1, kn = k0 + 32;
      gload_lds16(Ag + (size_t)r0 * K + kn + c0, As + nb * 4096 + wid * 512);
      gload_lds16(Ag + (size_t)r1 * K + kn + c1, As + nb * 4096 + 2048 + wid * 512);
      gload_lds16(Bg + (size_t)r0 * K + kn + c0, Bs + nb * 4096 + wid * 512);
      gload_lds16(Bg + (size_t)r1 * K + kn + c1, Bs + nb * 4096 + 2048 + wid * 512);
    }
    bf16x8 af[4], bfr[4];
#pragma unroll
    for (int mf = 0; mf < 4; ++mf)
      af[mf] = *(const bf16x8*)&As[cur * 4096 + (wr * 64 + mf * 16 + ml) * 32 + kg];
#pragma unroll
    for (int nf = 0; nf < 4; ++nf)
      bfr[nf] = *(const bf16x8*)&Bs[cur * 4096 + (wc * 64 + nf * 16 + ml) * 32 + kg];
#pragma unroll
    for (int mf = 0; mf < 4; ++mf)
#pragma unroll
      for (int nf = 0; nf < 4; ++nf)
        acc[mf][nf] = __builtin_amdgcn_mfma_f32_16x16x32_bf16(
            af[mf], bfr[nf], acc[mf][nf], 0, 0, 0);
    cur ^= 1;
  }

  __syncthreads();
  bf16* OT = (bf16*)smem; // [128][132] padded
  const int jrow0 = (lane >> 4) << 2;
  const int b = m0 >> 10, t0 = m0 & 1023;
  if (ybl < 8) { // Q or K: stage row-major (row=m, col=n)
#pragma unroll
    for (int nf = 0; nf < 4; ++nf) {
      const float bv = bias[n0 + wc * 64 + nf * 16 + ml];
#pragma unroll
      for (int mf = 0; mf < 4; ++mf)
#pragma unroll
        for (int j = 0; j < 4; ++j)
          OT[(wr * 64 + mf * 16 + jrow0 + j) * 132 + wc * 64 + nf * 16 + ml] =
              (bf16)(acc[mf][nf][j] + bv);
    }
    __syncthreads();
    bf16* dst = isq ? q_buf : k_buf;
    const int h0 = n0 >> 6;
#pragma unroll
    for (int it = 0; it < 8; ++it) {
      const int idx = it * 256 + tid;
      const int dg = idx & 7, r = (idx >> 3) & 127, hl = idx >> 10;
      *(bf16x8*)&dst[(((size_t)b * 8 + h0 + hl) * 1024 + t0 + r) * 64 + dg * 8] =
          *(const bf16x8*)&OT[r * 132 + hl * 64 + dg * 8];
    }
  } else { // V: stage col-major (row=n col, col=m) for t-contiguous stores
#pragma unroll
    for (int nf = 0; nf < 4; ++nf) {
      const float bv = bias[n0 + wc * 64 + nf * 16 + ml];
#pragma unroll
      for (int mf = 0; mf < 4; ++mf) {
        bf16x4 o;
#pragma unroll
        for (int j = 0; j < 4; ++j) o[j] = (bf16)(acc[mf][nf][j] + bv);
        *(bf16x4*)&OT[(wc * 64 + nf * 16 + ml) * 132 + wr * 64 + mf * 16 + jrow0] = o;
      }
    }
    __syncthreads();
    const int h0 = (n0 - 512) >> 6;
#pragma unroll
    for (int it = 0; it < 8; ++it) {
      const int idx = it * 256 + tid;
      const int og = idx & 15, c = idx >> 4;
      const int hl = c >> 6, d = c & 63;
      *(bf16x8*)&v_t[(((size_t)b * 8 + h0 + hl) * 64 + d) * 1024 + t0 + og * 8] =
          *(const bf16x8*)&OT[c * 132 + og * 8];
    }
  }
}

// ---------------------------------------------------------------------------
// Kernel 5: block-causal flash attention (unchanged from R2-R6).
// ---------------------------------------------------------------------------
__global__ __launch_bounds__(256)
void attn_k(const bf16* __restrict__ qb, const bf16* __restrict__ kb,
            const bf16* __restrict__ vt, bf16* __restrict__ y)
{
  __shared__ bf16 Ks[2][4096];
  __shared__ bf16 Vs[2][4096];
  __shared__ bf16 Ps[4][1024];
  const int tid = threadIdx.x, wid = tid >> 6, lane = tid & 63;
  const int L = blockIdx.x;
  const int xcd = L & 7, chunk = L >> 3;
  const int bh = xcd + ((chunk >> 4) << 3);
  const int qt = 15 - (chunk & 15);
  const int b = bh >> 3, h = bh & 7;
  const int t0 = qt << 6;
  const int ml = lane & 15, hi = lane >> 4, kg = hi << 3;

  const bf16* qrow = qb + ((size_t)bh * 1024 + t0 + wid * 16) * 64;
  bf16x8 aq[2];
  aq[0] = *(const bf16x8*)&qrow[ml * 64 + kg];
  aq[1] = *(const bf16x8*)&qrow[ml * 64 + 32 + kg];

  f32x4 accO[4] = {};
  float lsum[4] = {0.f, 0.f, 0.f, 0.f};

  const int nkt = ((qt >> 2) + 1) << 2;
  const bf16* kbase = kb + (size_t)bh * 1024 * 64;
  const bf16* vbase = vt + (size_t)bh * 64 * 1024;

  const int sr = (wid << 3) + (lane >> 3);
  const int sg = ((lane & 7) ^ ((lane >> 3) & 7)) << 3;
  bf16* pw = &Ps[wid][0];

  {
    gload_lds16(kbase + (size_t)sr * 64 + sg,          &Ks[0][wid * 512]);
    gload_lds16(kbase + (size_t)(sr + 32) * 64 + sg,   &Ks[0][2048 + wid * 512]);
    gload_lds16(vbase + (size_t)sr * 1024 + sg,        &Vs[0][wid * 512]);
    gload_lds16(vbase + (size_t)(sr + 32) * 1024 + sg, &Vs[0][2048 + wid * 512]);
  }

  int cur = 0;
  for (int kt = 0; kt < nkt; ++kt) {
    __syncthreads();
    if (kt + 1 < nkt) {
      const int tk0 = (kt + 1) << 6;
      const int nb = cur ^ 1;
      gload_lds16(kbase + (size_t)(tk0 + sr) * 64 + sg,        &Ks[nb][wid * 512]);
      gload_lds16(kbase + (size_t)(tk0 + sr + 32) * 64 + sg,   &Ks[nb][2048 + wid * 512]);
      gload_lds16(vbase + (size_t)sr * 1024 + tk0 + sg,        &Vs[nb][wid * 512]);
      gload_lds16(vbase + (size_t)(sr + 32) * 1024 + tk0 + sg, &Vs[nb][2048 + wid * 512]);
    }

    f32x4 sa[4] = {};
#pragma unroll
    for (int nf = 0; nf < 4; ++nf) {
      const int row = nf * 16 + ml;
#pragma unroll
      for (int ks = 0; ks < 2; ++ks) {
        const int g = ((ks * 4 + hi) ^ (ml & 7)) << 3;
        bf16x8 bk = *(const bf16x8*)&Ks[cur][row * 64 + g];
        sa[nf] = __builtin_amdgcn_mfma_f32_16x16x32_bf16(aq[ks], bk, sa[nf], 0, 0, 0);
      }
    }

#pragma unroll
    for (int nf = 0; nf < 4; ++nf) {
      const int gp0 = nf * 2 + (ml >> 3);
#pragma unroll
      for (int j = 0; j < 4; ++j) {
        const float p = __expf(sa[nf][j] * 0.125f);
        lsum[j] += p;
        const int prow = (hi << 2) + j;
        pw[prow * 64 + ((gp0 ^ (prow & 7)) << 3) + (ml & 7)] = (bf16)p;
      }
    }

#pragma unroll
    for (int ks = 0; ks < 2; ++ks) {
      const int g = ((ks * 4 + hi) ^ (ml & 7)) << 3;
      bf16x8 pa = *(const bf16x8*)&pw[ml * 64 + g];
#pragma unroll
      for (int df = 0; df < 4; ++df) {
        bf16x8 bv = *(const bf16x8*)&Vs[cur][(df * 16 + ml) * 64 + g];
        accO[df] = __builtin_amdgcn_mfma_f32_16x16x32_bf16(pa, bv, accO[df], 0, 0, 0);
      }
    }
    cur ^= 1;
  }

  float inv[4];
#pragma unroll
  for (int j = 0; j < 4; ++j) {
    float s = lsum[j];
#pragma unroll
    for (int off = 1; off < 16; off <<= 1) s += __shfl_xor(s, off);
    inv[j] = 1.f / s;
  }
#pragma unroll
  for (int df = 0; df < 4; ++df)
#pragma unroll
    for (int j = 0; j < 4; ++j) {
      const int t = t0 + wid * 16 + (hi << 2) + j;
      const int c = h * 64 + df * 16 + ml;
      y[((size_t)b * 1024 + t) * 512 + c] = (bf16)(accO[df][j] * inv[j]);
    }
}

// ---------------------------------------------------------------------------
extern "C" void kernel_launch(void* const* d_in, const int* in_sizes, int n_in,
                              void* d_out, int out_size, void* d_ws, size_t ws_size,
                              hipStream_t stream)
{
  const float* xi    = (const float*)d_in[0];
  const float* xc    = (const float*)d_in[1];
  const float* xj    = (const float*)d_in[2];
  const float* ln1_g = (const float*)d_in[3];
  const float* ln1_b = (const float*)d_in[4];
  const float* ln2_g = (const float*)d_in[5];
  const float* ln2_b = (const float*)d_in[6];
  const float* Wq    = (const float*)d_in[7];
  const float* bq    = (const float*)d_in[8];
  const float* Wkv   = (const float*)d_in[9];
  const float* bkv   = (const float*)d_in[10];
  const float* Wo    = (const float*)d_in[11];
  const float* bo    = (const float*)d_in[12];
  const float* Wfc   = (const float*)d_in[13];
  const float* bfc   = (const float*)d_in[14];
  const float* Wpr   = (const float*)d_in[15];
  const float* bpr   = (const float*)d_in[16];

  char* ws = (char*)d_ws;
  const size_t MB = 1ull << 20;
  bf16*  qs    = (bf16*)(ws + 0);
  bf16*  kvs   = (bf16*)(ws + 8 * MB);
  float* cs0   = (float*)(ws + 16 * MB);
  bf16*  WqT   = (bf16*)(ws + 32 * MB);
  bf16*  WkvT  = (bf16*)(ws + 32 * MB + 512 * 1024);
  bf16*  WoT   = (bf16*)(ws + 33 * MB + 512 * 1024);
  bf16*  WfcT  = (bf16*)(ws + 34 * MB);
  bf16*  WprT  = (bf16*)(ws + 36 * MB);
  bf16*  q_buf = (bf16*)(ws + 38 * MB);
  bf16*  k_buf = (bf16*)(ws + 46 * MB);
  bf16*  v_t   = (bf16*)(ws + 54 * MB);
  bf16*  yb    = (bf16*)(ws + 0);
  bf16*  hcs   = (bf16*)(ws + 8 * MB);
  bf16*  fcact = (bf16*)(ws + 38 * MB);
  float* cs    = cs0;

  prep_k<<<dim3(4608), 256, 0, stream>>>(Wq, Wkv, Wo, Wfc, Wpr,
                                         WqT, WkvT, WoT, WfcT, WprT,
                                         xi, xj, xc, ln1_g, ln1_b, qs, kvs, cs0);

  gemm_qkv_k<<<dim3(64, 12), 256, 0, stream>>>(qs, kvs, WqT, WkvT, bq, bkv,
                                               q_buf, k_buf, v_t);

  attn_k<<<dim3(1024), 256, 0, stream>>>(q_buf, k_buf, v_t, yb);

  gemmsk_k<EPI_O><<<dim3(64, 4), 512, 0, stream>>>(yb, WoT, bo, cs0,
                                                   (void*)cs, 512);

  ln2_k<<<dim3(2048), 256, 0, stream>>>(cs, ln2_g, ln2_b, hcs);

  gemm_fc_k<<<dim3(64, 16), 256, 0, stream>>>(hcs, WfcT, bfc, fcact);

  gemmsk_k<EPI_PR><<<dim3(64, 4), 512, 0, stream>>>(fcact, WprT, bpr, cs,
                                                    d_out, 2048);

  (void)in_sizes; (void)n_in; (void)out_size; (void)ws_size;
}

// Round 8
// 182.056 us; speedup vs baseline: 1.0557x; 1.0023x over previous
//
#include <hip/hip_runtime.h>
#include <hip/hip_bf16.h>
#include <math.h>

// ---------------------------------------------------------------------------
// CrossCausalAttentionBlock on MI355X (gfx950)
// B=8, T=1024 (V=4 blocks of 256), C=512, NH=8, hd=64
// R8: prep split into prep_w_k + prep_ln_k (ablation); LN thread owns 8
//     CONSECUTIVE channels -> bf16x8 / f32x4 vector stores (was 32 scalar
//     2B stores/thread, partial-line segments).
// ---------------------------------------------------------------------------

typedef __bf16 bf16;
typedef __bf16 bf16x8 __attribute__((ext_vector_type(8)));
typedef __bf16 bf16x4 __attribute__((ext_vector_type(4)));
typedef float  f32x4  __attribute__((ext_vector_type(4)));

__device__ __forceinline__ void gload_lds16(const void* g, void* l) {
  __builtin_amdgcn_global_load_lds(
      (__attribute__((address_space(1))) void*)(g),
      (__attribute__((address_space(3))) void*)(l), 16, 0, 0);
}

// ---------------------------------------------------------------------------
// Kernel 1a: weight converts fp32[K][N] -> bf16[N][K], 32x32 tiles.
// ---------------------------------------------------------------------------
__global__ __launch_bounds__(256)
void prep_w_k(const float* __restrict__ Wq, const float* __restrict__ Wkv,
              const float* __restrict__ Wo, const float* __restrict__ Wfc,
              const float* __restrict__ Wpr,
              bf16* __restrict__ WqT, bf16* __restrict__ WkvT,
              bf16* __restrict__ WoT, bf16* __restrict__ WfcT,
              bf16* __restrict__ WprT)
{
  __shared__ float tt[32][33];
  const int t = blockIdx.x;
  const int tid = threadIdx.x;
  const float* W; bf16* Wt; int K, N, lognx, tl;
  if (t < 256)       { W = Wq;  Wt = WqT;  K = 512;  N = 512;  lognx = 4; tl = t; }
  else if (t < 768)  { W = Wkv; Wt = WkvT; K = 512;  N = 1024; lognx = 5; tl = t - 256; }
  else if (t < 1024) { W = Wo;  Wt = WoT;  K = 512;  N = 512;  lognx = 4; tl = t - 768; }
  else if (t < 2048) { W = Wfc; Wt = WfcT; K = 512;  N = 2048; lognx = 6; tl = t - 1024; }
  else               { W = Wpr; Wt = WprT; K = 2048; N = 512;  lognx = 4; tl = t - 2048; }
  const int bx = tl & ((1 << lognx) - 1), by = tl >> lognx;
  const int x = tid & 31, y = tid >> 5;
  const int n0 = bx << 5, k0 = by << 5;
#pragma unroll
  for (int yy = y; yy < 32; yy += 8)
    tt[yy][x] = W[(size_t)(k0 + yy) * N + n0 + x];
  __syncthreads();
#pragma unroll
  for (int yy = y; yy < 32; yy += 8)
    Wt[(size_t)(n0 + yy) * K + k0 + x] = (bf16)tt[x][yy];
}

// ---------------------------------------------------------------------------
// Kernel 1b: gather [v,b,c,h,w] -> [b,t,c] + LN1. Register-resident; thread
// (q=tid&3, chb=tid>>2) owns 8 CONSECUTIVE channels cb=chb*8.. and 4 tokens
// -> vector stores (bf16x8 / 2x f32x4), 256B contiguous per wave-instr.
// ---------------------------------------------------------------------------
__global__ __launch_bounds__(256)
void prep_ln_k(const float* __restrict__ xi, const float* __restrict__ xj,
               const float* __restrict__ xc,
               const float* __restrict__ g, const float* __restrict__ bb,
               bf16* __restrict__ qs, bf16* __restrict__ kvs,
               float* __restrict__ cs0)
{
  __shared__ float red[4][32];
  const int tid = threadIdx.x;
  const int u = blockIdx.x;
  const int sel = u >> 9, bid = u & 511;
  const int hh = bid & 15, b = (bid >> 4) & 7, v = bid >> 7;
  const float* src = (sel == 0) ? xi : ((sel == 1) ? xj : xc);
  const size_t base = ((size_t)(v * 8 + b) * 512) * 256 + (size_t)hh * 16;
  const int q = tid & 3, chb = tid >> 2;
  const int wid = tid >> 6, lane = tid & 63;
  const int cb = chb << 3; // 8 consecutive channels

  // gamma/beta: 2 vector loads each (L2/L3-hot)
  float gr[8], br[8];
  *(f32x4*)&gr[0] = *(const f32x4*)&g[cb];
  *(f32x4*)&gr[4] = *(const f32x4*)&g[cb + 4];
  *(f32x4*)&br[0] = *(const f32x4*)&bb[cb];
  *(f32x4*)&br[4] = *(const f32x4*)&bb[cb + 4];

  // 8 ch x 4 tokens in registers
  f32x4 x[8];
#pragma unroll
  for (int k = 0; k < 8; ++k)
    x[k] = *(const f32x4*)&src[base + (size_t)(cb + k) * 256 + (q << 2)];

  // per-token partial stats
  float s[4] = {0.f, 0.f, 0.f, 0.f}, ss[4] = {0.f, 0.f, 0.f, 0.f};
#pragma unroll
  for (int k = 0; k < 8; ++k)
#pragma unroll
    for (int i = 0; i < 4; ++i) {
      s[i] += x[k][i];
      ss[i] += x[k][i] * x[k][i];
    }
  // reduce across same-q lanes of this wave (offsets preserve q-class)
#pragma unroll
  for (int off = 4; off < 64; off <<= 1)
#pragma unroll
    for (int i = 0; i < 4; ++i) {
      s[i] += __shfl_xor(s[i], off);
      ss[i] += __shfl_xor(ss[i], off);
    }
  // cross-wave combine via 512B LDS (entry e = q*4+i)
  if (lane < 16) {
    red[wid][(lane & 3) * 4 + (lane >> 2)]      = s[lane >> 2];
    red[wid][16 + (lane & 3) * 4 + (lane >> 2)] = ss[lane >> 2];
  }
  __syncthreads();
  float mu[4], rs[4];
#pragma unroll
  for (int i = 0; i < 4; ++i) {
    const int e = q * 4 + i;
    float st  = red[0][e] + red[1][e] + red[2][e] + red[3][e];
    float sst = red[0][16 + e] + red[1][16 + e] + red[2][16 + e] + red[3][16 + e];
    mu[i] = st * (1.f / 512.f);
    rs[i] = rsqrtf(sst * (1.f / 512.f) - mu[i] * mu[i] + 1e-5f);
  }
  // normalize + VECTOR stores (8 consecutive channels per token)
  const int tkb = v * 256 + hh * 16 + (q << 2);
  bf16* dstb = (sel == 0) ? qs : kvs;
#pragma unroll
  for (int i = 0; i < 4; ++i) {
    const size_t orow = ((size_t)b * 1024 + tkb + i) * 512;
    if (sel == 2) {
      f32x4 o0, o1;
#pragma unroll
      for (int k = 0; k < 4; ++k) {
        o0[k] = (x[k][i] - mu[i]) * rs[i] * gr[k] + br[k];
        o1[k] = (x[k + 4][i] - mu[i]) * rs[i] * gr[k + 4] + br[k + 4];
      }
      *(f32x4*)&cs0[orow + cb]     = o0;
      *(f32x4*)&cs0[orow + cb + 4] = o1;
    } else {
      bf16x8 o;
#pragma unroll
      for (int k = 0; k < 8; ++k)
        o[k] = (bf16)((x[k][i] - mu[i]) * rs[i] * gr[k] + br[k]);
      *(bf16x8*)&dstb[orow + cb] = o;
    }
  }
}

// ---------------------------------------------------------------------------
// Kernel 3: row LayerNorm(ln2) on cs f32[8192][512] -> hcs bf16. 1 wave/row.
// ---------------------------------------------------------------------------
__global__ __launch_bounds__(256)
void ln2_k(const float* __restrict__ cs, const float* __restrict__ g,
           const float* __restrict__ bb, bf16* __restrict__ hcs)
{
  const int tid = threadIdx.x, wid = tid >> 6, lane = tid & 63;
  const int row = blockIdx.x * 4 + wid;
  const float* x = cs + (size_t)row * 512 + lane * 8;
  float v[8];
  *(f32x4*)&v[0] = *(const f32x4*)&x[0];
  *(f32x4*)&v[4] = *(const f32x4*)&x[4];
  float s = 0.f, ss = 0.f;
#pragma unroll
  for (int k = 0; k < 8; ++k) { s += v[k]; ss += v[k] * v[k]; }
#pragma unroll
  for (int off = 1; off < 64; off <<= 1) {
    s += __shfl_xor(s, off);
    ss += __shfl_xor(ss, off);
  }
  const float mu = s * (1.f / 512.f);
  const float rstd = rsqrtf(ss * (1.f / 512.f) - mu * mu + 1e-5f);
  bf16x8 o;
#pragma unroll
  for (int k = 0; k < 8; ++k) {
    int ch = lane * 8 + k;
    o[k] = (bf16)((v[k] - mu) * rstd * g[ch] + bb[ch]);
  }
  *(bf16x8*)&hcs[(size_t)row * 512 + lane * 8] = o;
}

// ---------------------------------------------------------------------------
// Kernel 4: FC GEMM (M=8192, N=2048, K=512), 2-phase dbuf, GELU epilogue
// staged through padded LDS (stride 132) for full-line coalesced stores.
// ---------------------------------------------------------------------------
__global__ __launch_bounds__(256)
void gemm_fc_k(const bf16* __restrict__ A, const bf16* __restrict__ Bt,
               const float* __restrict__ bias, bf16* __restrict__ fo)
{
  const int K = 512;
  __shared__ __align__(16) char smem[34816];
  bf16* As = (bf16*)smem;            // [2][4096]
  bf16* Bs = (bf16*)(smem + 16384);  // [2][4096]
  const int tid = threadIdx.x;
  const int wid = tid >> 6, lane = tid & 63;
  const int wr = wid >> 1, wc = wid & 1;
  const int ml = lane & 15, kg = (lane >> 4) << 3;
  const int m0 = blockIdx.x * 128, n0 = blockIdx.y * 128;

  const int e0 = wid * 512 + lane * 8;
  const int r0 = e0 >> 5, c0 = e0 & 31;
  const int e1 = e0 + 2048;
  const int r1 = e1 >> 5, c1 = e1 & 31;

  const bf16* Ag = A + (size_t)m0 * K;
  const bf16* Bg = Bt + (size_t)n0 * K;

  f32x4 acc[4][4] = {};

  gload_lds16(Ag + (size_t)r0 * K + c0, As + wid * 512);
  gload_lds16(Ag + (size_t)r1 * K + c1, As + 2048 + wid * 512);
  gload_lds16(Bg + (size_t)r0 * K + c0, Bs + wid * 512);
  gload_lds16(Bg + (size_t)r1 * K + c1, Bs + 2048 + wid * 512);

  int cur = 0;
  for (int k0 = 0; k0 < K; k0 += 32) {
    __syncthreads();
    if (k0 + 32 < K) {
      const int nb = cur ^ 1, kn = k0 + 32;
      gload_lds16(Ag + (size_t)r0 * K + kn + c0, As + nb * 4096 + wid * 512);
      gload_lds16(Ag + (size_t)r1 * K + kn + c1, As + nb * 4096 + 2048 + wid * 512);
      gload_lds16(Bg + (size_t)r0 * K + kn + c0, Bs + nb * 4096 + wid * 512);
      gload_lds16(Bg + (size_t)r1 * K + kn + c1, Bs + nb * 4096 + 2048 + wid * 512);
    }
    bf16x8 af[4], bfr[4];
#pragma unroll
    for (int mf = 0; mf < 4; ++mf)
      af[mf] = *(const bf16x8*)&As[cur * 4096 + (wr * 64 + mf * 16 + ml) * 32 + kg];
#pragma unroll
    for (int nf = 0; nf < 4; ++nf)
      bfr[nf] = *(const bf16x8*)&Bs[cur * 4096 + (wc * 64 + nf * 16 + ml) * 32 + kg];
#pragma unroll
    for (int mf = 0; mf < 4; ++mf)
#pragma unroll
      for (int nf = 0; nf < 4; ++nf)
        acc[mf][nf] = __builtin_amdgcn_mfma_f32_16x16x32_bf16(
            af[mf], bfr[nf], acc[mf][nf], 0, 0, 0);
    cur ^= 1;
  }

  // GELU -> padded LDS tile (stride 132) -> coalesced 16B row stores
  __syncthreads();
  bf16* OT = (bf16*)smem; // [128][132]
  const int jrow0 = (lane >> 4) << 2;
#pragma unroll
  for (int nf = 0; nf < 4; ++nf) {
    const float bv = bias[n0 + wc * 64 + nf * 16 + ml];
#pragma unroll
    for (int mf = 0; mf < 4; ++mf)
#pragma unroll
      for (int j = 0; j < 4; ++j) {
        float x = acc[mf][nf][j] + bv;
        float u = 0.7978845608f * (x + 0.044715f * x * x * x);
        float e = __expf(2.f * u);
        float th = 1.f - 2.f / (e + 1.f);
        OT[(wr * 64 + mf * 16 + jrow0 + j) * 132 + wc * 64 + nf * 16 + ml] =
            (bf16)(0.5f * x * (1.f + th));
      }
  }
  __syncthreads();
#pragma unroll
  for (int it = 0; it < 8; ++it) {
    const int idx = it * 256 + tid;
    const int cg = idx & 15, r = idx >> 4;
    *(bf16x8*)&fo[(size_t)(m0 + r) * 2048 + n0 + cg * 8] =
        *(const bf16x8*)&OT[r * 132 + cg * 8];
  }
}

// ---------------------------------------------------------------------------
// Kernel 4b: in-block split-K GEMM for N=512 stages (O, PR). 512 threads,
// 2 wave-groups x K-half, 2-phase dbuf each; LDS combine; group 1 epilogues.
// ---------------------------------------------------------------------------
enum { EPI_O = 2, EPI_PR = 4 };

template <int EPI>
__global__ __launch_bounds__(512)
void gemmsk_k(const bf16* __restrict__ A, const bf16* __restrict__ Bt,
              const float* __restrict__ bias, const float* res,
              void* out0, int K)
{
  __shared__ __align__(16) char smem[131072];
  bf16*  AS = (bf16*)smem;
  bf16*  BS = (bf16*)(smem + 65536);
  float* CF = (float*)smem;

  const int tid = threadIdx.x;
  const int wid = tid >> 6, lane = tid & 63;
  const int half = wid >> 2, w2 = wid & 3;
  const int wr = w2 >> 1, wc = w2 & 1;
  const int ml = lane & 15, kg = (lane >> 4) << 3;
  const int m0 = blockIdx.x * 128, n0 = blockIdx.y * 128;
  const int Kh = K >> 1;

  const int e0 = w2 * 512 + lane * 8;
  const int r0 = e0 >> 5, c0 = e0 & 31;
  const int e1 = e0 + 2048;
  const int r1 = e1 >> 5, c1 = e1 & 31;

  const bf16* Ag = A + (size_t)m0 * K + half * Kh;
  const bf16* Bg = Bt + (size_t)n0 * K + half * Kh;
  bf16* A0 = AS + half * 4096;
  bf16* B0 = BS + half * 4096;

  f32x4 acc[4][4] = {};

  gload_lds16(Ag + (size_t)r0 * K + c0, A0 + w2 * 512);
  gload_lds16(Ag + (size_t)r1 * K + c1, A0 + 2048 + w2 * 512);
  gload_lds16(Bg + (size_t)r0 * K + c0, B0 + w2 * 512);
  gload_lds16(Bg + (size_t)r1 * K + c1, B0 + 2048 + w2 * 512);

  int cur = 0;
  for (int k0 = 0; k0 < Kh; k0 += 32) {
    __syncthreads();
    if (k0 + 32 < Kh) {
      const int kn = k0 + 32;
      bf16* An = AS + ((cur ^ 1) * 8192) + half * 4096;
      bf16* Bn = BS + ((cur ^ 1) * 8192) + half * 4096;
      gload_lds16(Ag + (size_t)r0 * K + kn + c0, An + w2 * 512);
      gload_lds16(Ag + (size_t)r1 * K + kn + c1, An + 2048 + w2 * 512);
      gload_lds16(Bg + (size_t)r0 * K + kn + c0, Bn + w2 * 512);
      gload_lds16(Bg + (size_t)r1 * K + kn + c1, Bn + 2048 + w2 * 512);
    }
    const bf16* Ac = AS + cur * 8192 + half * 4096;
    const bf16* Bc = BS + cur * 8192 + half * 4096;
    bf16x8 af[4], bfr[4];
#pragma unroll
    for (int mf = 0; mf < 4; ++mf)
      af[mf] = *(const bf16x8*)&Ac[(wr * 64 + mf * 16 + ml) * 32 + kg];
#pragma unroll
    for (int nf = 0; nf < 4; ++nf)
      bfr[nf] = *(const bf16x8*)&Bc[(wc * 64 + nf * 16 + ml) * 32 + kg];
#pragma unroll
    for (int mf = 0; mf < 4; ++mf)
#pragma unroll
      for (int nf = 0; nf < 4; ++nf)
        acc[mf][nf] = __builtin_amdgcn_mfma_f32_16x16x32_bf16(
            af[mf], bfr[nf], acc[mf][nf], 0, 0, 0);
    cur ^= 1;
  }

  const int jrow0 = (lane >> 4) << 2;
  __syncthreads();
  if (half == 0) {
#pragma unroll
    for (int mf = 0; mf < 4; ++mf)
#pragma unroll
      for (int nf = 0; nf < 4; ++nf)
#pragma unroll
        for (int j = 0; j < 4; ++j)
          CF[(wr * 64 + mf * 16 + jrow0 + j) * 128 + wc * 64 + nf * 16 + ml] =
              acc[mf][nf][j];
  }
  __syncthreads();
  if (half == 1) {
#pragma unroll
    for (int nf = 0; nf < 4; ++nf) {
      const int n = n0 + wc * 64 + nf * 16 + ml;
      const float bv = bias[n];
#pragma unroll
      for (int mf = 0; mf < 4; ++mf) {
        const int mbase = m0 + wr * 64 + mf * 16 + jrow0;
        float v4[4];
#pragma unroll
        for (int j = 0; j < 4; ++j)
          v4[j] = acc[mf][nf][j] +
                  CF[(wr * 64 + mf * 16 + jrow0 + j) * 128 + wc * 64 + nf * 16 + ml];
        if constexpr (EPI == EPI_O) {
          float* cs = (float*)out0;
#pragma unroll
          for (int j = 0; j < 4; ++j) {
            const size_t idx = (size_t)(mbase + j) * 512 + n;
            cs[idx] = v4[j] + bv + res[idx];
          }
        } else {
          float* out = (float*)out0;
          const int b = mbase >> 10, t = mbase & 1023;
          const int v = t >> 8, hhh = (t >> 4) & 15, w0 = t & 15;
          f32x4 o;
#pragma unroll
          for (int j = 0; j < 4; ++j)
            o[j] = v4[j] + bv + res[(size_t)(mbase + j) * 512 + n];
          *(f32x4*)&out[(((size_t)v * 8 + b) * 512 + n) * 256 + hhh * 16 + w0] = o;
        }
      }
    }
  }
}

// ---------------------------------------------------------------------------
// Kernel 4c: merged Q + KV projection GEMM, 2-phase dbuf, LDS-staged stores.
// Grid (64, 12): ybl 0-3 Q, 4-7 K, 8-11 V(transposed).
// ---------------------------------------------------------------------------
__global__ __launch_bounds__(256)
void gemm_qkv_k(const bf16* __restrict__ Aq, const bf16* __restrict__ Akv,
                const bf16* __restrict__ WqT, const bf16* __restrict__ WkvT,
                const float* __restrict__ bq, const float* __restrict__ bkv,
                bf16* __restrict__ q_buf, bf16* __restrict__ k_buf,
                bf16* __restrict__ v_t)
{
  const int K = 512;
  __shared__ __align__(16) char smem[34816];
  bf16* As = (bf16*)smem;
  bf16* Bs = (bf16*)(smem + 16384);
  const int tid = threadIdx.x;
  const int wid = tid >> 6, lane = tid & 63;
  const int wr = wid >> 1, wc = wid & 1;
  const int ml = lane & 15, kg = (lane >> 4) << 3;
  const int ybl = blockIdx.y;
  const bool isq = ybl < 4;
  const bf16* A     = isq ? Aq  : Akv;
  const bf16* Bt    = isq ? WqT : WkvT;
  const float* bias = isq ? bq : bkv;
  const int n0 = isq ? (ybl << 7) : ((ybl - 4) << 7);
  const int m0 = blockIdx.x * 128;

  const int e0 = wid * 512 + lane * 8;
  const int r0 = e0 >> 5, c0 = e0 & 31;
  const int e1 = e0 + 2048;
  const int r1 = e1 >> 5, c1 = e1 & 31;

  const bf16* Ag = A + (size_t)m0 * K;
  const bf16* Bg = Bt + (size_t)n0 * K;

  f32x4 acc[4][4] = {};

  gload_lds16(Ag + (size_t)r0 * K + c0, As + wid * 512);
  gload_lds16(Ag + (size_t)r1 * K + c1, As + 2048 + wid * 512);
  gload_lds16(Bg + (size_t)r0 * K + c0, Bs + wid * 512);
  gload_lds16(Bg + (size_t)r1 * K + c1, Bs + 2048 + wid * 512);

  int cur = 0;
  for (int k0 = 0; k0 < K; k0 += 32) {
    __syncthreads();
    if (k0 + 32 < K) {
      const int nb = cur ^ 1, kn = k0 + 32;
      gload_lds16(Ag + (size_t)r0 * K + kn + c0, As + nb * 4096 + wid * 512);
      gload_lds16(Ag + (size_t)r1 * K + kn + c1, As + nb * 4096 + 2048 + wid * 512);
      gload_lds16(Bg + (size_t)r0 * K + kn + c0, Bs + nb * 4096 + wid * 512);
      gload_lds16(Bg + (size_t)r1 * K + kn + c1, Bs + nb * 4096 + 2048 + wid * 512);
    }
    bf16x8 af[4], bfr[4];
#pragma unroll
    for (int mf = 0; mf < 4; ++mf)
      af[mf] = *(const bf16x8*)&As[cur * 4096 + (wr * 64 + mf * 16 + ml) * 32 + kg];
#pragma unroll
    for (int nf = 0; nf < 4; ++nf)
      bfr[nf] = *(const bf16x8*)&Bs[cur * 4096 + (wc * 64 + nf * 16 + ml) * 32 + kg];
#pragma unroll
    for (int mf = 0; mf < 4; ++mf)
#pragma unroll
      for (int nf = 0; nf < 4; ++nf)
        acc[mf][nf] = __builtin_amdgcn_mfma_f32_16x16x32_bf16(
            af[mf], bfr[nf], acc[mf][nf], 0, 0, 0);
    cur ^= 1;
  }

  __syncthreads();
  bf16* OT = (bf16*)smem; // [128][132] padded
  const int jrow0 = (lane >> 4) << 2;
  const int b = m0 >> 10, t0 = m0 & 1023;
  if (ybl < 8) { // Q or K: stage row-major (row=m, col=n)
#pragma unroll
    for (int nf = 0; nf < 4; ++nf) {
      const float bv = bias[n0 + wc * 64 + nf * 16 + ml];
#pragma unroll
      for (int mf = 0; mf < 4; ++mf)
#pragma unroll
        for (int j = 0; j < 4; ++j)
          OT[(wr * 64 + mf * 16 + jrow0 + j) * 132 + wc * 64 + nf * 16 + ml] =
              (bf16)(acc[mf][nf][j] + bv);
    }
    __syncthreads();
    bf16* dst = isq ? q_buf : k_buf;
    const int h0 = n0 >> 6;
#pragma unroll
    for (int it = 0; it < 8; ++it) {
      const int idx = it * 256 + tid;
      const int dg = idx & 7, r = (idx >> 3) & 127, hl = idx >> 10;
      *(bf16x8*)&dst[(((size_t)b * 8 + h0 + hl) * 1024 + t0 + r) * 64 + dg * 8] =
          *(const bf16x8*)&OT[r * 132 + hl * 64 + dg * 8];
    }
  } else { // V: stage col-major (row=n col, col=m) for t-contiguous stores
#pragma unroll
    for (int nf = 0; nf < 4; ++nf) {
      const float bv = bias[n0 + wc * 64 + nf * 16 + ml];
#pragma unroll
      for (int mf = 0; mf < 4; ++mf) {
        bf16x4 o;
#pragma unroll
        for (int j = 0; j < 4; ++j) o[j] = (bf16)(acc[mf][nf][j] + bv);
        *(bf16x4*)&OT[(wc * 64 + nf * 16 + ml) * 132 + wr * 64 + mf * 16 + jrow0] = o;
      }
    }
    __syncthreads();
    const int h0 = (n0 - 512) >> 6;
#pragma unroll
    for (int it = 0; it < 8; ++it) {
      const int idx = it * 256 + tid;
      const int og = idx & 15, c = idx >> 4;
      const int hl = c >> 6, d = c & 63;
      *(bf16x8*)&v_t[(((size_t)b * 8 + h0 + hl) * 64 + d) * 1024 + t0 + og * 8] =
          *(const bf16x8*)&OT[c * 132 + og * 8];
    }
  }
}

// ---------------------------------------------------------------------------
// Kernel 5: block-causal flash attention (unchanged from R2-R7).
// ---------------------------------------------------------------------------
__global__ __launch_bounds__(256)
void attn_k(const bf16* __restrict__ qb, const bf16* __restrict__ kb,
            const bf16* __restrict__ vt, bf16* __restrict__ y)
{
  __shared__ bf16 Ks[2][4096];
  __shared__ bf16 Vs[2][4096];
  __shared__ bf16 Ps[4][1024];
  const int tid = threadIdx.x, wid = tid >> 6, lane = tid & 63;
  const int L = blockIdx.x;
  const int xcd = L & 7, chunk = L >> 3;
  const int bh = xcd + ((chunk >> 4) << 3);
  const int qt = 15 - (chunk & 15);
  const int b = bh >> 3, h = bh & 7;
  const int t0 = qt << 6;
  const int ml = lane & 15, hi = lane >> 4, kg = hi << 3;

  const bf16* qrow = qb + ((size_t)bh * 1024 + t0 + wid * 16) * 64;
  bf16x8 aq[2];
  aq[0] = *(const bf16x8*)&qrow[ml * 64 + kg];
  aq[1] = *(const bf16x8*)&qrow[ml * 64 + 32 + kg];

  f32x4 accO[4] = {};
  float lsum[4] = {0.f, 0.f, 0.f, 0.f};

  const int nkt = ((qt >> 2) + 1) << 2;
  const bf16* kbase = kb + (size_t)bh * 1024 * 64;
  const bf16* vbase = vt + (size_t)bh * 64 * 1024;

  const int sr = (wid << 3) + (lane >> 3);
  const int sg = ((lane & 7) ^ ((lane >> 3) & 7)) << 3;
  bf16* pw = &Ps[wid][0];

  {
    gload_lds16(kbase + (size_t)sr * 64 + sg,          &Ks[0][wid * 512]);
    gload_lds16(kbase + (size_t)(sr + 32) * 64 + sg,   &Ks[0][2048 + wid * 512]);
    gload_lds16(vbase + (size_t)sr * 1024 + sg,        &Vs[0][wid * 512]);
    gload_lds16(vbase + (size_t)(sr + 32) * 1024 + sg, &Vs[0][2048 + wid * 512]);
  }

  int cur = 0;
  for (int kt = 0; kt < nkt; ++kt) {
    __syncthreads();
    if (kt + 1 < nkt) {
      const int tk0 = (kt + 1) << 6;
      const int nb = cur ^ 1;
      gload_lds16(kbase + (size_t)(tk0 + sr) * 64 + sg,        &Ks[nb][wid * 512]);
      gload_lds16(kbase + (size_t)(tk0 + sr + 32) * 64 + sg,   &Ks[nb][2048 + wid * 512]);
      gload_lds16(vbase + (size_t)sr * 1024 + tk0 + sg,        &Vs[nb][wid * 512]);
      gload_lds16(vbase + (size_t)(sr + 32) * 1024 + tk0 + sg, &Vs[nb][2048 + wid * 512]);
    }

    f32x4 sa[4] = {};
#pragma unroll
    for (int nf = 0; nf < 4; ++nf) {
      const int row = nf * 16 + ml;
#pragma unroll
      for (int ks = 0; ks < 2; ++ks) {
        const int g = ((ks * 4 + hi) ^ (ml & 7)) << 3;
        bf16x8 bk = *(const bf16x8*)&Ks[cur][row * 64 + g];
        sa[nf] = __builtin_amdgcn_mfma_f32_16x16x32_bf16(aq[ks], bk, sa[nf], 0, 0, 0);
      }
    }

#pragma unroll
    for (int nf = 0; nf < 4; ++nf) {
      const int gp0 = nf * 2 + (ml >> 3);
#pragma unroll
      for (int j = 0; j < 4; ++j) {
        const float p = __expf(sa[nf][j] * 0.125f);
        lsum[j] += p;
        const int prow = (hi << 2) + j;
        pw[prow * 64 + ((gp0 ^ (prow & 7)) << 3) + (ml & 7)] = (bf16)p;
      }
    }

#pragma unroll
    for (int ks = 0; ks < 2; ++ks) {
      const int g = ((ks * 4 + hi) ^ (ml & 7)) << 3;
      bf16x8 pa = *(const bf16x8*)&pw[ml * 64 + g];
#pragma unroll
      for (int df = 0; df < 4; ++df) {
        bf16x8 bv = *(const bf16x8*)&Vs[cur][(df * 16 + ml) * 64 + g];
        accO[df] = __builtin_amdgcn_mfma_f32_16x16x32_bf16(pa, bv, accO[df], 0, 0, 0);
      }
    }
    cur ^= 1;
  }

  float inv[4];
#pragma unroll
  for (int j = 0; j < 4; ++j) {
    float s = lsum[j];
#pragma unroll
    for (int off = 1; off < 16; off <<= 1) s += __shfl_xor(s, off);
    inv[j] = 1.f / s;
  }
#pragma unroll
  for (int df = 0; df < 4; ++df)
#pragma unroll
    for (int j = 0; j < 4; ++j) {
      const int t = t0 + wid * 16 + (hi << 2) + j;
      const int c = h * 64 + df * 16 + ml;
      y[((size_t)b * 1024 + t) * 512 + c] = (bf16)(accO[df][j] * inv[j]);
    }
}

// ---------------------------------------------------------------------------
extern "C" void kernel_launch(void* const* d_in, const int* in_sizes, int n_in,
                              void* d_out, int out_size, void* d_ws, size_t ws_size,
                              hipStream_t stream)
{
  const float* xi    = (const float*)d_in[0];
  const float* xc    = (const float*)d_in[1];
  const float* xj    = (const float*)d_in[2];
  const float* ln1_g = (const float*)d_in[3];
  const float* ln1_b = (const float*)d_in[4];
  const float* ln2_g = (const float*)d_in[5];
  const float* ln2_b = (const float*)d_in[6];
  const float* Wq    = (const float*)d_in[7];
  const float* bq    = (const float*)d_in[8];
  const float* Wkv   = (const float*)d_in[9];
  const float* bkv   = (const float*)d_in[10];
  const float* Wo    = (const float*)d_in[11];
  const float* bo    = (const float*)d_in[12];
  const float* Wfc   = (const float*)d_in[13];
  const float* bfc   = (const float*)d_in[14];
  const float* Wpr   = (const float*)d_in[15];
  const float* bpr   = (const float*)d_in[16];

  char* ws = (char*)d_ws;
  const size_t MB = 1ull << 20;
  bf16*  qs    = (bf16*)(ws + 0);
  bf16*  kvs   = (bf16*)(ws + 8 * MB);
  float* cs0   = (float*)(ws + 16 * MB);
  bf16*  WqT   = (bf16*)(ws + 32 * MB);
  bf16*  WkvT  = (bf16*)(ws + 32 * MB + 512 * 1024);
  bf16*  WoT   = (bf16*)(ws + 33 * MB + 512 * 1024);
  bf16*  WfcT  = (bf16*)(ws + 34 * MB);
  bf16*  WprT  = (bf16*)(ws + 36 * MB);
  bf16*  q_buf = (bf16*)(ws + 38 * MB);
  bf16*  k_buf = (bf16*)(ws + 46 * MB);
  bf16*  v_t   = (bf16*)(ws + 54 * MB);
  bf16*  yb    = (bf16*)(ws + 0);
  bf16*  hcs   = (bf16*)(ws + 8 * MB);
  bf16*  fcact = (bf16*)(ws + 38 * MB);
  float* cs    = cs0;

  prep_w_k<<<dim3(3072), 256, 0, stream>>>(Wq, Wkv, Wo, Wfc, Wpr,
                                           WqT, WkvT, WoT, WfcT, WprT);
  prep_ln_k<<<dim3(1536), 256, 0, stream>>>(xi, xj, xc, ln1_g, ln1_b,
                                            qs, kvs, cs0);

  gemm_qkv_k<<<dim3(64, 12), 256, 0, stream>>>(qs, kvs, WqT, WkvT, bq, bkv,
                                               q_buf, k_buf, v_t);

  attn_k<<<dim3(1024), 256, 0, stream>>>(q_buf, k_buf, v_t, yb);

  gemmsk_k<EPI_O><<<dim3(64, 4), 512, 0, stream>>>(yb, WoT, bo, cs0,
                                                   (void*)cs, 512);

  ln2_k<<<dim3(2048), 256, 0, stream>>>(cs, ln2_g, ln2_b, hcs);

  gemm_fc_k<<<dim3(64, 16), 256, 0, stream>>>(hcs, WfcT, bfc, fcact);

  gemmsk_k<EPI_PR><<<dim3(64, 4), 512, 0, stream>>>(fcact, WprT, bpr, cs,
                                                    d_out, 2048);

  (void)in_sizes; (void)n_in; (void)out_size; (void)ws_size;
}